// Round 2
// baseline (843.187 us; speedup 1.0000x reference)
//
#include <hip/hip_runtime.h>
#include <cstddef>
#include <cstdint>

#define HID     128
#define NHEAD   4
#define DHEAD   32
#define NPAPER  100000
#define NAUTHOR 50000
#define NEDGE   250000
#define BATCH_PAPER  50000
#define BATCH_AUTHOR 25000
#define NPAD    100032          // NPAPER padded to x64
#define NAPAD   50048           // NAUTHOR padded to x64
#define NTOT    150080          // NPAD + NAPAD

typedef unsigned short bf16;   // raw bf16 storage
typedef __attribute__((ext_vector_type(8))) short v8s;   // 8 bf16 (4 VGPRs)
typedef __attribute__((ext_vector_type(4))) float v4f;   // 4 fp32 acc

__device__ __forceinline__ float b2f(bf16 u) {
    union { unsigned int i; float f; } v; v.i = ((unsigned int)u) << 16; return v.f;
}
__device__ __forceinline__ bf16 f2b(float f) {
    unsigned int x = __float_as_uint(f);
    unsigned int r = x + 0x7fffu + ((x >> 16) & 1u);   // round-to-nearest-even
    return (bf16)(r >> 16);
}
__device__ __forceinline__ float4 ld4(const float* p) { return *(const float4*)p; }
__device__ __forceinline__ float4 ld4(const bf16* p) {
    ushort4 u = *(const ushort4*)p;
    return make_float4(b2f(u.x), b2f(u.y), b2f(u.z), b2f(u.w));
}
__device__ __forceinline__ void st4(float* p, float4 v) { *(float4*)p = v; }
__device__ __forceinline__ void st4(bf16* p, float4 v) {
    *(ushort4*)p = make_ushort4(f2b(v.x), f2b(v.y), f2b(v.z), f2b(v.w));
}
__device__ __forceinline__ float gelu_f(float x) {
    return 0.5f * x * (1.f + erff(x * 0.70710678118654752f));
}

// canonical bf16 weight-block element offsets
enum { O_LINW=0, O_LINB=16384, O_KW=16512, O_KB=82048, O_QW=82560, O_QB=148096,
       O_VW=148608, O_VB=214144, O_AREL=214656, O_MREL=239232, O_PREL=263808,
       O_SKIP=263832, O_AW=263836, O_AB=329372, O_WTOT=329884 };

// ---------------------------------------------------------------------------
__global__ void detect_kernel(const void* __restrict__ prel, int* __restrict__ flag)
{
    if (threadIdx.x == 0 && blockIdx.x == 0) {
        unsigned int w = *(const unsigned int*)prel;
        flag[0] = (w == 0x3F803F80u) ? 1 : 0;
    }
}

__global__ __launch_bounds__(256) void convert_weights(
    const void* lin_w, const void* lin_b, const void* k_w, const void* k_b,
    const void* q_w, const void* q_b, const void* v_w, const void* v_b,
    const void* a_rel, const void* m_rel, const void* p_rel, const void* skip,
    const void* a_w, const void* a_b,
    bf16* __restrict__ WB, const int* __restrict__ flag)
{
    int tid = blockIdx.x * 256 + threadIdx.x;
    if (tid >= O_WTOT) return;
    bool bf = flag[0] != 0;
    const void* src; int off = tid;
    if      (off < 16384)            { src = lin_w; }
    else if ((off -= 16384) < 128)   { src = lin_b; }
    else if ((off -= 128) < 65536)   { src = k_w; }
    else if ((off -= 65536) < 512)   { src = k_b; }
    else if ((off -= 512) < 65536)   { src = q_w; }
    else if ((off -= 65536) < 512)   { src = q_b; }
    else if ((off -= 512) < 65536)   { src = v_w; }
    else if ((off -= 65536) < 512)   { src = v_b; }
    else if ((off -= 512) < 24576)   { src = a_rel; }
    else if ((off -= 24576) < 24576) { src = m_rel; }
    else if ((off -= 24576) < 24)    { src = p_rel; }
    else if ((off -= 24) < 4)        { src = skip; }
    else if ((off -= 4) < 65536)     { src = a_w; }
    else                             { off -= 65536; src = a_b; }
    WB[tid] = bf ? ((const bf16*)src)[off] : f2b(((const float*)src)[off]);
}

// transpose the 9 static weights: WTS[m][n*128+k] = W_m[k*128+n]
// m: 0=lin_w, 1..4=q_w(l*2+t), 5..8=a_w(l*2+t)
__global__ __launch_bounds__(256) void transpose_static(
    const bf16* __restrict__ WB, bf16* __restrict__ WTS)
{
    int tid = blockIdx.x * 256 + threadIdx.x;
    if (tid >= 9 * 16384) return;
    int mtx = tid >> 14, idx = tid & 16383;
    int n = idx >> 7, k = idx & 127;
    int off = (mtx == 0) ? O_LINW
            : (mtx < 5)  ? O_QW + (mtx - 1) * 16384
                         : O_AW + (mtx - 5) * 16384;
    WTS[(size_t)mtx * 16384 + n * 128 + k] = WB[off + k * 128 + n];
}

__global__ __launch_bounds__(256) void bias_prep(
    const bf16* __restrict__ WB, float* __restrict__ BF32)
{
    int tid = blockIdx.x * 256 + threadIdx.x;
    if (tid >= 9 * 128) return;
    int m = tid >> 7, j = tid & 127;
    int off = (m == 0) ? O_LINB : (m < 5 ? O_QB + (m-1)*128 : O_AB + (m-5)*128);
    BF32[tid] = b2f(WB[off + j]);
}

// ---------------------------------------------------------------------------
// Fused MFMA projection GEMM, column-split waves + B-in-registers.
//   32-row tile, 256 thr = 4 waves; wave w owns output cols [w*32, w*32+32).
//   Small LDS (16.9 KB) + launch_bounds(256,8) targets VGPR<=64 for 8
//   blocks/CU (32 waves) occupancy.
//   A staged in fragment-contiguous LDS layout (chunk d = [rb|ks|quad|m]):
//   staging writes and ds_read_b128 fragment reads are lane-linear.
//   C staged through LDS (bf16, bias pre-added) for 16B/lane coalesced
//   stores; diagonal remap (cc = (c8+r)&15) kills read conflicts.
// NOUT=1: C0 = A@W0^T + b0  (W0/b0 selected per block by row0<BND: a else b)
// NOUT=2: C0 = A@W0a^T + b0a, C1 = A@W1^T + b1   (two sequential passes)
// AMODE: 0 = A bf16, rows guaranteed padded (unguarded loads/stores)
//        2 = A dynamic dtype (d_in, flag), guarded by N
// ---------------------------------------------------------------------------
#define CSTB 136    // bf16 C-staging row stride (elements)
#define CSTF 132    // fp32 C-staging row stride (elements, gemm_epi)

template <int AMODE, int NOUT>
__global__ __launch_bounds__(256, 8) void gemm_proj(
    const void* __restrict__ A,
    const bf16* __restrict__ WT0a, const bf16* __restrict__ WT0b,
    const float* __restrict__ b0a, const float* __restrict__ b0b,
    const bf16* __restrict__ WT1, const float* __restrict__ b1,
    bf16* __restrict__ C0, bf16* __restrict__ C1,
    int N, int BND, const int* __restrict__ flag)
{
    __shared__ __align__(16) bf16 As[32 * 128];   // 8 KB fragment-contiguous
    __shared__ __align__(16) bf16 Cs[32 * CSTB];  // 8.7 KB
    const int t = threadIdx.x;
    const int row0 = blockIdx.x * 32;
    const bf16*  WT0 = (row0 < BND) ? WT0a : WT0b;
    const float* b0  = (row0 < BND) ? b0a  : b0b;

    // ---- stage A: chunk d holds A[row0 + rb*16+m][(ks*4+q)*8 .. +8) ----
    if (AMODE == 0) {
        #pragma unroll
        for (int s = 0; s < 2; ++s) {
            int d = t + s * 256;
            int m_ = d & 15, q_ = (d >> 4) & 3, ks_ = (d >> 6) & 3, rb_ = (d >> 8) & 1;
            int gr = row0 + rb_ * 16 + m_;
            *(uint4*)&As[d * 8] =
                *(const uint4*)((const bf16*)A + (size_t)gr * 128 + (ks_ * 4 + q_) * 8);
        }
    } else {
        bool a_bf = flag[0] != 0;
        #pragma unroll
        for (int s = 0; s < 2; ++s) {
            int d = t + s * 256;
            int m_ = d & 15, q_ = (d >> 4) & 3, ks_ = (d >> 6) & 3, rb_ = (d >> 8) & 1;
            int gr = row0 + rb_ * 16 + m_;
            int c8 = ks_ * 4 + q_;
            bf16* dst = &As[d * 8];
            if (gr < N) {
                if (a_bf) {
                    *(uint4*)dst = *(const uint4*)((const bf16*)A + (size_t)gr * 128 + c8 * 8);
                } else {
                    const float* ap = (const float*)A + (size_t)gr * 128 + c8 * 8;
                    float4 x = *(const float4*)ap, y = *(const float4*)(ap + 4);
                    ((ushort4*)dst)[0] = make_ushort4(f2b(x.x), f2b(x.y), f2b(x.z), f2b(x.w));
                    ((ushort4*)dst)[1] = make_ushort4(f2b(y.x), f2b(y.y), f2b(y.z), f2b(y.w));
                }
            } else {
                *(uint4*)dst = make_uint4(0, 0, 0, 0);
            }
        }
    }
    __syncthreads();

    const int lane = t & 63;
    const int wave = t >> 6;
    const int m    = lane & 15;
    const int quad = lane >> 4;
    const int colbase = wave * 32;

    auto pass = [&](const bf16* __restrict__ WT, const float* __restrict__ bias,
                    bf16* __restrict__ C, bool needBar) {
        float bv0 = bias[colbase + m];
        float bv1 = bias[colbase + 16 + m];
        v8s bfrag[2][4];
        #pragma unroll
        for (int c2 = 0; c2 < 2; ++c2)
            #pragma unroll
            for (int ks = 0; ks < 4; ++ks)
                bfrag[c2][ks] = *(const v8s*)&WT[
                    (size_t)(colbase + c2 * 16 + m) * 128 + ks * 32 + quad * 8];
        if (needBar) __syncthreads();           // pass-1 copy-out readers done

        #pragma unroll
        for (int rb = 0; rb < 2; ++rb) {
            v4f a0 = (v4f){0.f, 0.f, 0.f, 0.f};
            v4f a1 = (v4f){0.f, 0.f, 0.f, 0.f};
            #pragma unroll
            for (int ks = 0; ks < 4; ++ks) {
                v8s av = *(const v8s*)&As[(((rb * 4 + ks) << 6) + lane) * 8];
                a0 = __builtin_amdgcn_mfma_f32_16x16x32_bf16(av, bfrag[0][ks], a0, 0, 0, 0);
                a1 = __builtin_amdgcn_mfma_f32_16x16x32_bf16(av, bfrag[1][ks], a1, 0, 0, 0);
            }
            #pragma unroll
            for (int rg = 0; rg < 4; ++rg) {
                int row = rb * 16 + quad * 4 + rg;
                Cs[row * CSTB + colbase + m]      = f2b(a0[rg] + bv0);
                Cs[row * CSTB + colbase + 16 + m] = f2b(a1[rg] + bv1);
            }
        }
        __syncthreads();
        #pragma unroll
        for (int s = 0; s < 2; ++s) {
            int idx = t + s * 256;
            int r = idx >> 4, c8 = idx & 15;
            int cc = (c8 + r) & 15;             // diagonal: conflict-free Cs reads
            int gr = row0 + r;
            if (AMODE == 0 || gr < N)
                *(uint4*)(C + (size_t)gr * 128 + cc * 8) =
                    *(const uint4*)&Cs[r * CSTB + cc * 8];
        }
    };

    pass(WT0, b0, C0, false);
    if (NOUT == 2) pass(WT1, b1, C1, true);
}

// ---------------------------------------------------------------------------
// Fused epilogue GEMM: XS = g*(gelu(scale*ACC)@W^T + b) + (1-g)*XS
// 32-row tile, column-split B-in-registers; fp32 C staging preserves the
// skip-blend numerics exactly. XS skip rows prefetched to registers during
// staging (latency hides under MFMA). In-place on XS.
// ---------------------------------------------------------------------------
__global__ __launch_bounds__(256, 8) void gemm_epi(
    const float* __restrict__ ACC,
    const bf16* __restrict__ WTa, const bf16* __restrict__ WTb,
    const float* __restrict__ ba, const float* __restrict__ bb,
    const bf16* __restrict__ skv,     // [0]=paper gate, [1]=author gate
    bf16* __restrict__ XS, int BND)
{
    __shared__ __align__(16) bf16  As[32 * 128];   // 8 KB fragment-contiguous
    __shared__ __align__(16) float Cs[32 * CSTF];  // 16.9 KB
    const int t = threadIdx.x;
    const int row0 = blockIdx.x * 32;
    bool paper = row0 < BND;
    const bf16*  WT   = paper ? WTa : WTb;
    const float* bias = paper ? ba : bb;
    float scale = paper ? 0.5f : 1.0f;      // mean over {2,1} edge types
    float sv = b2f(paper ? skv[0] : skv[1]);
    float g = 1.f / (1.f + expf(-sv)), gm = 1.f - g;

    #pragma unroll
    for (int s = 0; s < 2; ++s) {            // stage gelu(scale*ACC) as bf16
        int d = t + s * 256;
        int m_ = d & 15, q_ = (d >> 4) & 3, ks_ = (d >> 6) & 3, rb_ = (d >> 8) & 1;
        int gr = row0 + rb_ * 16 + m_;
        const float* ap = ACC + (size_t)gr * 128 + (ks_ * 4 + q_) * 8;
        float4 x = *(const float4*)ap, y = *(const float4*)(ap + 4);
        x.x = gelu_f(scale*x.x); x.y = gelu_f(scale*x.y);
        x.z = gelu_f(scale*x.z); x.w = gelu_f(scale*x.w);
        y.x = gelu_f(scale*y.x); y.y = gelu_f(scale*y.y);
        y.z = gelu_f(scale*y.z); y.w = gelu_f(scale*y.w);
        bf16* dst = &As[d * 8];
        ((ushort4*)dst)[0] = make_ushort4(f2b(x.x), f2b(x.y), f2b(x.z), f2b(x.w));
        ((ushort4*)dst)[1] = make_ushort4(f2b(y.x), f2b(y.y), f2b(y.z), f2b(y.w));
    }

    // prefetch skip-input XS rows (registers; latency hides under MFMA)
    ushort4 xpre[4];
    #pragma unroll
    for (int s = 0; s < 4; ++s) {
        int idx = t + s * 256;
        int r = idx >> 5, c = (idx & 31) * 4;
        xpre[s] = *(const ushort4*)(XS + (size_t)(row0 + r) * 128 + c);
    }

    const int lane = t & 63;
    const int wave = t >> 6;
    const int m    = lane & 15;
    const int quad = lane >> 4;
    const int colbase = wave * 32;

    float bv0 = bias[colbase + m];
    float bv1 = bias[colbase + 16 + m];
    v8s bfrag[2][4];
    #pragma unroll
    for (int c2 = 0; c2 < 2; ++c2)
        #pragma unroll
        for (int ks = 0; ks < 4; ++ks)
            bfrag[c2][ks] = *(const v8s*)&WT[
                (size_t)(colbase + c2 * 16 + m) * 128 + ks * 32 + quad * 8];
    __syncthreads();

    #pragma unroll
    for (int rb = 0; rb < 2; ++rb) {
        v4f a0 = (v4f){0.f, 0.f, 0.f, 0.f};
        v4f a1 = (v4f){0.f, 0.f, 0.f, 0.f};
        #pragma unroll
        for (int ks = 0; ks < 4; ++ks) {
            v8s av = *(const v8s*)&As[(((rb * 4 + ks) << 6) + lane) * 8];
            a0 = __builtin_amdgcn_mfma_f32_16x16x32_bf16(av, bfrag[0][ks], a0, 0, 0, 0);
            a1 = __builtin_amdgcn_mfma_f32_16x16x32_bf16(av, bfrag[1][ks], a1, 0, 0, 0);
        }
        #pragma unroll
        for (int rg = 0; rg < 4; ++rg) {
            int row = rb * 16 + quad * 4 + rg;
            Cs[row * CSTF + colbase + m]      = a0[rg] + bv0;
            Cs[row * CSTF + colbase + 16 + m] = a1[rg] + bv1;
        }
    }
    __syncthreads();

    #pragma unroll
    for (int s = 0; s < 4; ++s) {
        int idx = t + s * 256;
        int r = idx >> 5, c = (idx & 31) * 4;
        int gr = row0 + r;
        float4 o  = *(const float4*)&Cs[r * CSTF + c];
        float4 xo = make_float4(b2f(xpre[s].x), b2f(xpre[s].y),
                                b2f(xpre[s].z), b2f(xpre[s].w));
        o.x = g*o.x + gm*xo.x; o.y = g*o.y + gm*xo.y;
        o.z = g*o.z + gm*xo.z; o.w = g*o.w + gm*xo.w;
        st4(XS + (size_t)gr * 128 + c, o);
    }
}

// ---------------------------------------------------------------------------
// WCT[c][n*128+k] = (W @ blockdiag(rel))^T bf16;  BC[c] = b @ blockdiag(rel)
// ---------------------------------------------------------------------------
__global__ __launch_bounds__(256) void combine_kernel(
    const bf16* __restrict__ kw, const bf16* __restrict__ kb,
    const bf16* __restrict__ vw, const bf16* __restrict__ vb,
    const bf16* __restrict__ arel, const bf16* __restrict__ mrel,
    int l, bf16* __restrict__ WCT, float* __restrict__ BC)
{
    __shared__ float Rs[4096];
    int c = blockIdx.x;
    int e = c >> 1;
    int which = c & 1;
    int styp = (e == 0) ? 1 : 0;
    const bf16* W = (which ? vw : kw) + (size_t)(l*2 + styp) * (HID*HID);
    const bf16* B = (which ? vb : kb) + (size_t)(l*2 + styp) * HID;
    const bf16* R = (which ? mrel : arel) + (size_t)(l*3 + e) * (NHEAD*DHEAD*DHEAD);

    for (int s = threadIdx.x; s < 4096; s += 256) Rs[s] = b2f(R[s]);
    __syncthreads();

    int j = threadIdx.x & 127;
    int half = threadIdx.x >> 7;
    int h = j >> 5, jj = j & 31;
    const float* Rh = &Rs[h*1024 + jj];

    for (int k = half*64; k < half*64 + 64; ++k) {
        float sum = 0.f;
        #pragma unroll
        for (int dq = 0; dq < 8; ++dq) {
            float4 wv = ld4(W + k*HID + h*DHEAD + dq*4);
            sum += wv.x * Rh[(dq*4+0)*32] + wv.y * Rh[(dq*4+1)*32]
                 + wv.z * Rh[(dq*4+2)*32] + wv.w * Rh[(dq*4+3)*32];
        }
        WCT[(size_t)c*16384 + j*128 + k] = f2b(sum);
    }
    if (half == 0) {
        float sum = 0.f;
        #pragma unroll
        for (int dq = 0; dq < 8; ++dq) {
            float4 bv4 = ld4(B + h*DHEAD + dq*4);
            sum += bv4.x * Rh[(dq*4+0)*32] + bv4.y * Rh[(dq*4+1)*32]
                 + bv4.z * Rh[(dq*4+2)*32] + bv4.w * Rh[(dq*4+3)*32];
        }
        BC[c*128 + j] = sum;
    }
}

// ---------------------------------------------------------------------------
// CSR build
// ---------------------------------------------------------------------------
__global__ __launch_bounds__(256) void hist_kernel(
    const int* __restrict__ dst, int* __restrict__ cnt,
    int* __restrict__ rank, int nE)
{
    int i = blockIdx.x * 256 + threadIdx.x;
    if (i < nE) rank[i] = atomicAdd(&cnt[dst[i]], 1);
}

__global__ __launch_bounds__(256) void scan1_kernel(
    const int* __restrict__ cnt, int* __restrict__ off,
    int* __restrict__ bsum, int n)
{
    __shared__ int s[256];
    int i = blockIdx.x * 256 + threadIdx.x;
    int v = (i < n) ? cnt[i] : 0;
    s[threadIdx.x] = v; __syncthreads();
    for (int d = 1; d < 256; d <<= 1) {
        int t = (threadIdx.x >= d) ? s[threadIdx.x - d] : 0;
        __syncthreads();
        s[threadIdx.x] += t;
        __syncthreads();
    }
    if (i < n) off[i] = s[threadIdx.x] - v;
    if (threadIdx.x == 255) bsum[blockIdx.x] = s[255];
}

__global__ __launch_bounds__(512) void scan2_kernel(int* __restrict__ bsum, int nb)
{
    __shared__ int s[512];
    int v = (threadIdx.x < nb) ? bsum[threadIdx.x] : 0;
    s[threadIdx.x] = v; __syncthreads();
    for (int d = 1; d < 512; d <<= 1) {
        int t = (threadIdx.x >= d) ? s[threadIdx.x - d] : 0;
        __syncthreads();
        s[threadIdx.x] += t;
        __syncthreads();
    }
    if (threadIdx.x < nb) bsum[threadIdx.x] = s[threadIdx.x] - v;
}

__global__ __launch_bounds__(256) void scan3_kernel(
    int* __restrict__ off, const int* __restrict__ bsum, int n)
{
    int i = blockIdx.x * 256 + threadIdx.x;
    if (i < n) off[i] += bsum[blockIdx.x];
}

__global__ __launch_bounds__(256) void fill_kernel(
    const int* __restrict__ src, const int* __restrict__ dst,
    const int* __restrict__ off, const int* __restrict__ rank,
    int* __restrict__ csr, int nE)
{
    int i = blockIdx.x * 256 + threadIdx.x;
    if (i < nE) csr[off[dst[i]] + rank[i]] = src[i];
}

// ---------------------------------------------------------------------------
// Fused edge kernel (gather form) with CSR index prefetch
// ---------------------------------------------------------------------------
__global__ __launch_bounds__(256) void edge_gather(
    const bf16* __restrict__ Q, const bf16* __restrict__ K,
    const bf16* __restrict__ V, const int* __restrict__ off,
    const int* __restrict__ csr, const bf16* __restrict__ prel,
    float* __restrict__ ACC, int Nd, int nE, int add)
{
    int tid = blockIdx.x * 256 + threadIdx.x;
    int g = tid >> 5;
    if (g >= Nd) return;
    int j = tid & 31;
    int beg = off[g];
    int end = (g == Nd - 1) ? nE : off[g + 1];

    float4 qv = ld4(Q + (size_t)g*128 + j*4);
    float ph = b2f(prel[j >> 3]) * 0.17677669529663687f;

    float4 num = make_float4(0.f, 0.f, 0.f, 0.f);
    float den = 0.f;
    int sidx = (beg < end) ? csr[beg] : 0;
    for (int t = beg; t < end; ++t) {
        int snext = (t + 1 < end) ? csr[t + 1] : 0;
        float4 kv = ld4(K + (size_t)sidx*128 + j*4);
        float4 vv = ld4(V + (size_t)sidx*128 + j*4);
        float p = qv.x*kv.x + qv.y*kv.y + qv.z*kv.z + qv.w*kv.w;
        p += __shfl_xor(p, 1);
        p += __shfl_xor(p, 2);
        p += __shfl_xor(p, 4);
        float ex = expf(p * ph);
        den += ex;
        num.x += ex*vv.x; num.y += ex*vv.y; num.z += ex*vv.z; num.w += ex*vv.w;
        sidx = snext;
    }
    float inv = 1.f / (den + 1e-16f);
    float4 r = make_float4(num.x*inv, num.y*inv, num.z*inv, num.w*inv);
    float* o = &ACC[(size_t)g*128 + j*4];
    if (add) { float4 old = *(float4*)o; r.x+=old.x; r.y+=old.y; r.z+=old.z; r.w+=old.w; }
    *(float4*)o = r;
}

// ---------------------------------------------------------------------------
__global__ __launch_bounds__(256) void gather_embed(
    const void* __restrict__ T, const int* __restrict__ idx,
    bf16* __restrict__ out, int n, const int* __restrict__ flag)
{
    int tid = blockIdx.x * 256 + threadIdx.x;
    int row = tid >> 4, c = tid & 15;
    if (row >= n) return;
    bool bf = flag[0] != 0;
    int srow = idx[row];
    bf16* o = out + (size_t)tid * 8;
    if (bf) {
        *(uint4*)o = ((const uint4*)T)[(size_t)srow*16 + c];
    } else {
        const float* s = (const float*)T + (size_t)srow*128 + c*8;
        float4 x = *(const float4*)s, y = *(const float4*)(s + 4);
        ((ushort4*)o)[0] = make_ushort4(f2b(x.x), f2b(x.y), f2b(x.z), f2b(x.w));
        ((ushort4*)o)[1] = make_ushort4(f2b(y.x), f2b(y.y), f2b(y.z), f2b(y.w));
    }
}

__global__ __launch_bounds__(256) void copy_out(
    const bf16* __restrict__ XS, void* __restrict__ out, int total8,
    const int* __restrict__ flag)
{
    int tid = blockIdx.x * 256 + threadIdx.x;
    if (tid >= total8) return;
    bool bf = flag[0] != 0;
    const int np8 = BATCH_PAPER * 16;
    const bf16* s = (tid < np8) ? (XS + (size_t)tid * 8)
                                : (XS + (size_t)NPAD * 128 + (size_t)(tid - np8) * 8);
    if (bf) {
        ((uint4*)out)[tid] = *(const uint4*)s;
    } else {
        float* o = (float*)out + (size_t)tid * 8;
        *(float4*)o = make_float4(b2f(s[0]), b2f(s[1]), b2f(s[2]), b2f(s[3]));
        *(float4*)(o + 4) = make_float4(b2f(s[4]), b2f(s[5]), b2f(s[6]), b2f(s[7]));
    }
}

// ---------------------------------------------------------------------------
extern "C" void kernel_launch(void* const* d_in, const int* in_sizes, int n_in,
                              void* d_out, int out_size, void* d_ws, size_t ws_size,
                              hipStream_t stream)
{
    const void* x_paper    = d_in[0];
    const int*  author_idx = (const int*)d_in[1];
    const void* embed      = d_in[2];
    const int* esrc[3] = { (const int*)d_in[17], (const int*)d_in[19], (const int*)d_in[21] };
    const int* edst[3] = { (const int*)d_in[18], (const int*)d_in[20], (const int*)d_in[22] };

    // workspace (256B-aligned carve-outs), ~211 MB
    uint8_t* p = (uint8_t*)d_ws;
    auto take = [&](size_t bytes) {
        uint8_t* q = p; p += (bytes + 255) & ~(size_t)255; return q;
    };
    bf16*  XS   = (bf16*) take((size_t)NTOT * HID * 2);   // papers | authors (padded)
    bf16*  Q    = (bf16*) take((size_t)NTOT * HID * 2);
    bf16*  KREL = (bf16*) take((size_t)NPAD * HID * 2);
    bf16*  VREL = (bf16*) take((size_t)NPAD * HID * 2);
    float* ACC  = (float*)take((size_t)NTOT * HID * 4);
    bf16*  WCT  = (bf16*) take((size_t)6 * 16384 * 2);
    float* BC   = (float*)take((size_t)6 * 128 * 4);
    bf16*  WB   = (bf16*) take((size_t)O_WTOT * 2);
    bf16*  WTS  = (bf16*) take((size_t)9 * 16384 * 2);
    float* BF32 = (float*)take((size_t)9 * 128 * 4);
    int*   flag = (int*)  take(256);
    int Ndv[3] = { NPAPER, NAUTHOR, NPAPER };
    int* CSRoff[3];
    for (int e = 0; e < 3; ++e) CSRoff[e] = (int*)take((size_t)Ndv[e] * 4);
    int* CSRsrc[3];
    for (int e = 0; e < 3; ++e) CSRsrc[e] = (int*)take((size_t)NEDGE * 4);
    int* rankb = (int*)take((size_t)NEDGE * 4);
    int* cntb  = (int*)take((size_t)NPAPER * 4);
    int* bsumb = (int*)take((size_t)512 * 4);

    bf16* XSa = XS + (size_t)NPAD * HID;    // author region
    bf16* Qa  = Q  + (size_t)NPAD * HID;
    float* ACCa = ACC + (size_t)NPAD * HID;

    detect_kernel<<<1, 64, 0, stream>>>(d_in[13], flag);
    convert_weights<<<(O_WTOT + 255)/256, 256, 0, stream>>>(
        d_in[3], d_in[4], d_in[5], d_in[6], d_in[7], d_in[8], d_in[9], d_in[10],
        d_in[11], d_in[12], d_in[13], d_in[14], d_in[15], d_in[16], WB, flag);
    transpose_static<<<(9*16384 + 255)/256, 256, 0, stream>>>(WB, WTS);
    bias_prep<<<(9*128 + 255)/256, 256, 0, stream>>>(WB, BF32);

    // ---- CSR per edge type ----
    const int EB = (NEDGE + 255) / 256;
    for (int e = 0; e < 3; ++e) {
        int Nd = Ndv[e];
        int nb = (Nd + 255) / 256;
        hipMemsetAsync(cntb, 0, (size_t)Nd * sizeof(int), stream);
        hist_kernel<<<EB, 256, 0, stream>>>(edst[e], cntb, rankb, NEDGE);
        scan1_kernel<<<nb, 256, 0, stream>>>(cntb, CSRoff[e], bsumb, Nd);
        scan2_kernel<<<1, 512, 0, stream>>>(bsumb, nb);
        scan3_kernel<<<nb, 256, 0, stream>>>(CSRoff[e], bsumb, Nd);
        fill_kernel<<<EB, 256, 0, stream>>>(esrc[e], edst[e], CSRoff[e], rankb,
                                            CSRsrc[e], NEDGE);
    }

    // ---- input projections ----
    gemm_proj<2,1><<<(NPAPER + 31)/32, 256, 0, stream>>>(
        x_paper, WTS, WTS, BF32, BF32, nullptr, nullptr,
        XS, nullptr, NPAPER, NPAD, flag);
    gather_embed<<<(NAUTHOR*16 + 255)/256, 256, 0, stream>>>(embed, author_idx, XSa, NAUTHOR, flag);

    for (int l = 0; l < 2; ++l) {
        combine_kernel<<<6, 256, 0, stream>>>(WB + O_KW, WB + O_KB, WB + O_VW, WB + O_VB,
                                              WB + O_AREL, WB + O_MREL, l, WCT, BC);
        // fused Q projection (papers + authors, per-block weight select)
        gemm_proj<0,1><<<NTOT/32, 256, 0, stream>>>(
            XS, WTS + (size_t)(1 + l*2)*16384, WTS + (size_t)(1 + l*2 + 1)*16384,
            BF32 + (1 + l*2)*128, BF32 + (1 + l*2 + 1)*128, nullptr, nullptr,
            Q, nullptr, NTOT, NPAD, flag);

        for (int e = 0; e < 3; ++e) {
            const bf16* xsrc = (e == 0) ? XSa : XS;
            int Nsrc         = (e == 0) ? NAPAD : NPAD;
            const bf16* Qd   = (e == 1) ? Qa : Q;
            float* ACCd      = (e == 1) ? ACCa : ACC;
            int Nd = Ndv[e];
            int add = (e == 2) ? 1 : 0;

            // dual-output K/V projection
            gemm_proj<0,2><<<Nsrc/32, 256, 0, stream>>>(
                xsrc, WCT + (size_t)(2*e)*16384, WCT + (size_t)(2*e)*16384,
                BC + (2*e)*128, BC + (2*e)*128,
                WCT + (size_t)(2*e+1)*16384, BC + (2*e+1)*128,
                KREL, VREL, Nsrc, Nsrc + 64, flag);
            edge_gather<<<(Nd*32 + 255)/256, 256, 0, stream>>>(
                Qd, KREL, VREL, CSRoff[e], CSRsrc[e],
                WB + O_PREL + (l*3+e)*4, ACCd, Nd, NEDGE, add);
        }

        // fused epilogue (gelu+mean-scale+GEMM+skip, papers+authors, in-place)
        gemm_epi<<<NTOT/32, 256, 0, stream>>>(
            ACC, WTS + (size_t)(5 + l*2)*16384, WTS + (size_t)(5 + l*2 + 1)*16384,
            BF32 + (5 + l*2)*128, BF32 + (5 + l*2 + 1)*128,
            WB + O_SKIP + l*2, XS, NPAD);
    }

    int total8 = (BATCH_PAPER + BATCH_AUTHOR) * 16;
    copy_out<<<(total8 + 255)/256, 256, 0, stream>>>(XS, d_out, total8, flag);
}

// Round 4
// 744.033 us; speedup vs baseline: 1.1333x; 1.1333x over previous
//
#include <hip/hip_runtime.h>
#include <cstddef>
#include <cstdint>

#define HID     128
#define NHEAD   4
#define DHEAD   32
#define NPAPER  100000
#define NAUTHOR 50000
#define NEDGE   250000
#define BATCH_PAPER  50000
#define BATCH_AUTHOR 25000
#define NPAD    100032          // NPAPER padded to x64
#define NAPAD   50048           // NAUTHOR padded to x64
#define NTOT    150080          // NPAD + NAPAD

typedef unsigned short bf16;   // raw bf16 storage
typedef __attribute__((ext_vector_type(8))) short v8s;   // 8 bf16 (4 VGPRs)
typedef __attribute__((ext_vector_type(4))) float v4f;   // 4 fp32 acc

__device__ __forceinline__ float b2f(bf16 u) {
    union { unsigned int i; float f; } v; v.i = ((unsigned int)u) << 16; return v.f;
}
__device__ __forceinline__ bf16 f2b(float f) {
    unsigned int x = __float_as_uint(f);
    unsigned int r = x + 0x7fffu + ((x >> 16) & 1u);   // round-to-nearest-even
    return (bf16)(r >> 16);
}
__device__ __forceinline__ float4 ld4(const float* p) { return *(const float4*)p; }
__device__ __forceinline__ float4 ld4(const bf16* p) {
    ushort4 u = *(const ushort4*)p;
    return make_float4(b2f(u.x), b2f(u.y), b2f(u.z), b2f(u.w));
}
__device__ __forceinline__ void st4(float* p, float4 v) { *(float4*)p = v; }
__device__ __forceinline__ void st4(bf16* p, float4 v) {
    *(ushort4*)p = make_ushort4(f2b(v.x), f2b(v.y), f2b(v.z), f2b(v.w));
}
__device__ __forceinline__ float gelu_f(float x) {
    return 0.5f * x * (1.f + erff(x * 0.70710678118654752f));
}

// canonical bf16 weight-block element offsets
enum { O_LINW=0, O_LINB=16384, O_KW=16512, O_KB=82048, O_QW=82560, O_QB=148096,
       O_VW=148608, O_VB=214144, O_AREL=214656, O_MREL=239232, O_PREL=263808,
       O_SKIP=263832, O_AW=263836, O_AB=329372, O_WTOT=329884 };

// ---------------------------------------------------------------------------
__global__ void detect_kernel(const void* __restrict__ prel, int* __restrict__ flag)
{
    if (threadIdx.x == 0 && blockIdx.x == 0) {
        unsigned int w = *(const unsigned int*)prel;
        flag[0] = (w == 0x3F803F80u) ? 1 : 0;
    }
}

__global__ __launch_bounds__(256) void convert_weights(
    const void* lin_w, const void* lin_b, const void* k_w, const void* k_b,
    const void* q_w, const void* q_b, const void* v_w, const void* v_b,
    const void* a_rel, const void* m_rel, const void* p_rel, const void* skip,
    const void* a_w, const void* a_b,
    bf16* __restrict__ WB, const int* __restrict__ flag)
{
    int tid = blockIdx.x * 256 + threadIdx.x;
    if (tid >= O_WTOT) return;
    bool bf = flag[0] != 0;
    const void* src; int off = tid;
    if      (off < 16384)            { src = lin_w; }
    else if ((off -= 16384) < 128)   { src = lin_b; }
    else if ((off -= 128) < 65536)   { src = k_w; }
    else if ((off -= 65536) < 512)   { src = k_b; }
    else if ((off -= 512) < 65536)   { src = q_w; }
    else if ((off -= 65536) < 512)   { src = q_b; }
    else if ((off -= 512) < 65536)   { src = v_w; }
    else if ((off -= 65536) < 512)   { src = v_b; }
    else if ((off -= 512) < 24576)   { src = a_rel; }
    else if ((off -= 24576) < 24576) { src = m_rel; }
    else if ((off -= 24576) < 24)    { src = p_rel; }
    else if ((off -= 24) < 4)        { src = skip; }
    else if ((off -= 4) < 65536)     { src = a_w; }
    else                             { off -= 65536; src = a_b; }
    WB[tid] = bf ? ((const bf16*)src)[off] : f2b(((const float*)src)[off]);
}

// transpose the 9 static weights: WTS[m][n*128+k] = W_m[k*128+n]
// m: 0=lin_w, 1..4=q_w(l*2+t), 5..8=a_w(l*2+t)
__global__ __launch_bounds__(256) void transpose_static(
    const bf16* __restrict__ WB, bf16* __restrict__ WTS)
{
    int tid = blockIdx.x * 256 + threadIdx.x;
    if (tid >= 9 * 16384) return;
    int mtx = tid >> 14, idx = tid & 16383;
    int n = idx >> 7, k = idx & 127;
    int off = (mtx == 0) ? O_LINW
            : (mtx < 5)  ? O_QW + (mtx - 1) * 16384
                         : O_AW + (mtx - 5) * 16384;
    WTS[(size_t)mtx * 16384 + n * 128 + k] = WB[off + k * 128 + n];
}

__global__ __launch_bounds__(256) void bias_prep(
    const bf16* __restrict__ WB, float* __restrict__ BF32)
{
    int tid = blockIdx.x * 256 + threadIdx.x;
    if (tid >= 9 * 128) return;
    int m = tid >> 7, j = tid & 127;
    int off = (m == 0) ? O_LINB : (m < 5 ? O_QB + (m-1)*128 : O_AB + (m-5)*128);
    BF32[tid] = b2f(WB[off + j]);
}

// ---------------------------------------------------------------------------
// Fused MFMA projection GEMM, column-split waves + B-in-registers.
//   64-row tile, 256 thr = 4 waves; wave w owns output cols [w*32, w*32+32).
//   B fragments (8 x v8s = 32 VGPR) preloaded once per output pass ->
//   inner loop is LDS-only A-fragment reads + MFMA.
//   A staged in fragment-contiguous LDS layout (chunk d = [rb|ks|quad|m]).
//   C staged through LDS (bf16, bias pre-added) for 16B/lane coalesced
//   stores; diagonal remap (cc = (c8+r)&15) kills read conflicts.
//   Both passes select weights per block by row0<BND (a else b).
//   cstr: output row stride in elements (128 normal, 256 for interleaved KV).
// AMODE: 0 = A bf16, rows guaranteed padded (unguarded loads/stores)
//        2 = A dynamic dtype (d_in, flag), guarded by N
// ---------------------------------------------------------------------------
#define CSTB 136    // bf16 C-staging row stride (elements)
#define CSTF 132    // fp32 C-staging row stride (elements, gemm_epi)

template <int AMODE, int NOUT>
__global__ __launch_bounds__(256) void gemm_proj(
    const void* __restrict__ A,
    const bf16* __restrict__ WT0a, const bf16* __restrict__ WT0b,
    const float* __restrict__ b0a, const float* __restrict__ b0b,
    const bf16* __restrict__ WT1a, const bf16* __restrict__ WT1b,
    const float* __restrict__ b1a, const float* __restrict__ b1b,
    bf16* __restrict__ C0, bf16* __restrict__ C1, int cstr,
    int N, int BND, const int* __restrict__ flag)
{
    __shared__ __align__(16) bf16 As[64 * 128];   // 16 KB fragment-contiguous
    __shared__ __align__(16) bf16 Cs[64 * CSTB];  // 17.4 KB
    const int t = threadIdx.x;
    const int row0 = blockIdx.x * 64;
    const bool sela = row0 < BND;
    const bf16*  WT0 = sela ? WT0a : WT0b;
    const float* b0  = sela ? b0a  : b0b;

    // ---- stage A: chunk d holds A[row0 + rb*16+m][(ks*4+q)*8 .. +8) ----
    if (AMODE == 0) {
        #pragma unroll
        for (int s = 0; s < 4; ++s) {
            int d = t + s * 256;
            int m_ = d & 15, q_ = (d >> 4) & 3, ks_ = (d >> 6) & 3, rb_ = d >> 8;
            int gr = row0 + rb_ * 16 + m_;
            *(uint4*)&As[d * 8] =
                *(const uint4*)((const bf16*)A + (size_t)gr * 128 + (ks_ * 4 + q_) * 8);
        }
    } else {
        bool a_bf = flag[0] != 0;
        #pragma unroll
        for (int s = 0; s < 4; ++s) {
            int d = t + s * 256;
            int m_ = d & 15, q_ = (d >> 4) & 3, ks_ = (d >> 6) & 3, rb_ = d >> 8;
            int gr = row0 + rb_ * 16 + m_;
            int c8 = ks_ * 4 + q_;
            bf16* dst = &As[d * 8];
            if (gr < N) {
                if (a_bf) {
                    *(uint4*)dst = *(const uint4*)((const bf16*)A + (size_t)gr * 128 + c8 * 8);
                } else {
                    const float* ap = (const float*)A + (size_t)gr * 128 + c8 * 8;
                    float4 x = *(const float4*)ap, y = *(const float4*)(ap + 4);
                    ((ushort4*)dst)[0] = make_ushort4(f2b(x.x), f2b(x.y), f2b(x.z), f2b(x.w));
                    ((ushort4*)dst)[1] = make_ushort4(f2b(y.x), f2b(y.y), f2b(y.z), f2b(y.w));
                }
            } else {
                *(uint4*)dst = make_uint4(0, 0, 0, 0);
            }
        }
    }
    __syncthreads();

    const int lane = t & 63;
    const int wave = t >> 6;
    const int m    = lane & 15;
    const int quad = lane >> 4;
    const int colbase = wave * 32;

    auto pass = [&](const bf16* __restrict__ WT, const float* __restrict__ bias,
                    bf16* __restrict__ C, bool needBar) {
        float bv0 = bias[colbase + m];
        float bv1 = bias[colbase + 16 + m];
        v8s bfrag[2][4];
        #pragma unroll
        for (int c2 = 0; c2 < 2; ++c2)
            #pragma unroll
            for (int ks = 0; ks < 4; ++ks)
                bfrag[c2][ks] = *(const v8s*)&WT[
                    (size_t)(colbase + c2 * 16 + m) * 128 + ks * 32 + quad * 8];
        if (needBar) __syncthreads();           // pass-1 copy-out readers done

        #pragma unroll
        for (int rb = 0; rb < 4; ++rb) {
            v4f a0 = (v4f){0.f, 0.f, 0.f, 0.f};
            v4f a1 = (v4f){0.f, 0.f, 0.f, 0.f};
            #pragma unroll
            for (int ks = 0; ks < 4; ++ks) {
                v8s av = *(const v8s*)&As[(((rb * 4 + ks) << 6) + lane) * 8];
                a0 = __builtin_amdgcn_mfma_f32_16x16x32_bf16(av, bfrag[0][ks], a0, 0, 0, 0);
                a1 = __builtin_amdgcn_mfma_f32_16x16x32_bf16(av, bfrag[1][ks], a1, 0, 0, 0);
            }
            #pragma unroll
            for (int rg = 0; rg < 4; ++rg) {
                int row = rb * 16 + quad * 4 + rg;
                Cs[row * CSTB + colbase + m]      = f2b(a0[rg] + bv0);
                Cs[row * CSTB + colbase + 16 + m] = f2b(a1[rg] + bv1);
            }
        }
        __syncthreads();
        #pragma unroll
        for (int s = 0; s < 4; ++s) {
            int idx = t + s * 256;
            int r = idx >> 4, c8 = idx & 15;
            int cc = (c8 + r) & 15;             // diagonal: conflict-free Cs reads
            int gr = row0 + r;
            if (AMODE == 0 || gr < N)
                *(uint4*)(C + (size_t)gr * cstr + cc * 8) =
                    *(const uint4*)&Cs[r * CSTB + cc * 8];
        }
    };

    pass(WT0, b0, C0, false);
    if (NOUT == 2) {
        const bf16*  WT1 = sela ? WT1a : WT1b;
        const float* b1  = sela ? b1a  : b1b;
        pass(WT1, b1, C1, true);
    }
}

// ---------------------------------------------------------------------------
// Fused epilogue GEMM: XS = g*(gelu(scale*ACC)@W^T + b) + (1-g)*XS
// 64-row tile, column-split B-in-registers; fp32 C staging (aliasing As to
// keep LDS at 33.8 KB -> 4 blocks/CU) preserves skip-blend numerics exactly.
// XS skip rows prefetched to registers during staging. In-place on XS.
// ---------------------------------------------------------------------------
__global__ __launch_bounds__(256) void gemm_epi(
    const float* __restrict__ ACC,
    const bf16* __restrict__ WTa, const bf16* __restrict__ WTb,
    const float* __restrict__ ba, const float* __restrict__ bb,
    const bf16* __restrict__ skv,     // [0]=paper gate, [1]=author gate
    bf16* __restrict__ XS, int BND)
{
    __shared__ __align__(16) float Cs[64 * CSTF];  // 33.8 KB; As aliases front
    bf16* As = (bf16*)Cs;                          // 64*128*2 = 16 KB
    const int t = threadIdx.x;
    const int row0 = blockIdx.x * 64;
    bool paper = row0 < BND;
    const bf16*  WT   = paper ? WTa : WTb;
    const float* bias = paper ? ba : bb;
    float scale = paper ? 0.5f : 1.0f;      // mean over {2,1} edge types
    float sv = b2f(paper ? skv[0] : skv[1]);
    float g = 1.f / (1.f + expf(-sv)), gm = 1.f - g;

    #pragma unroll
    for (int s = 0; s < 4; ++s) {            // stage gelu(scale*ACC) as bf16
        int d = t + s * 256;
        int m_ = d & 15, q_ = (d >> 4) & 3, ks_ = (d >> 6) & 3, rb_ = d >> 8;
        int gr = row0 + rb_ * 16 + m_;
        const float* ap = ACC + (size_t)gr * 128 + (ks_ * 4 + q_) * 8;
        float4 x = *(const float4*)ap, y = *(const float4*)(ap + 4);
        x.x = gelu_f(scale*x.x); x.y = gelu_f(scale*x.y);
        x.z = gelu_f(scale*x.z); x.w = gelu_f(scale*x.w);
        y.x = gelu_f(scale*y.x); y.y = gelu_f(scale*y.y);
        y.z = gelu_f(scale*y.z); y.w = gelu_f(scale*y.w);
        bf16* dst = &As[d * 8];
        ((ushort4*)dst)[0] = make_ushort4(f2b(x.x), f2b(x.y), f2b(x.z), f2b(x.w));
        ((ushort4*)dst)[1] = make_ushort4(f2b(y.x), f2b(y.y), f2b(y.z), f2b(y.w));
    }

    // prefetch skip-input XS rows (registers; latency hides under MFMA)
    ushort4 xpre[8];
    #pragma unroll
    for (int s = 0; s < 8; ++s) {
        int idx = t + s * 256;
        int r = idx >> 5, c = (idx & 31) * 4;
        xpre[s] = *(const ushort4*)(XS + (size_t)(row0 + r) * 128 + c);
    }

    const int lane = t & 63;
    const int wave = t >> 6;
    const int m    = lane & 15;
    const int quad = lane >> 4;
    const int colbase = wave * 32;

    float bv0 = bias[colbase + m];
    float bv1 = bias[colbase + 16 + m];
    v8s bfrag[2][4];
    #pragma unroll
    for (int c2 = 0; c2 < 2; ++c2)
        #pragma unroll
        for (int ks = 0; ks < 4; ++ks)
            bfrag[c2][ks] = *(const v8s*)&WT[
                (size_t)(colbase + c2 * 16 + m) * 128 + ks * 32 + quad * 8];
    __syncthreads();                               // As staged

    v4f acc[4][2];
    #pragma unroll
    for (int rb = 0; rb < 4; ++rb) {
        v4f a0 = (v4f){0.f, 0.f, 0.f, 0.f};
        v4f a1 = (v4f){0.f, 0.f, 0.f, 0.f};
        #pragma unroll
        for (int ks = 0; ks < 4; ++ks) {
            v8s av = *(const v8s*)&As[(((rb * 4 + ks) << 6) + lane) * 8];
            a0 = __builtin_amdgcn_mfma_f32_16x16x32_bf16(av, bfrag[0][ks], a0, 0, 0, 0);
            a1 = __builtin_amdgcn_mfma_f32_16x16x32_bf16(av, bfrag[1][ks], a1, 0, 0, 0);
        }
        acc[rb][0] = a0; acc[rb][1] = a1;
    }
    __syncthreads();                               // all As reads done (alias!)

    #pragma unroll
    for (int rb = 0; rb < 4; ++rb)
        #pragma unroll
        for (int rg = 0; rg < 4; ++rg) {
            int row = rb * 16 + quad * 4 + rg;
            Cs[row * CSTF + colbase + m]      = acc[rb][0][rg] + bv0;
            Cs[row * CSTF + colbase + 16 + m] = acc[rb][1][rg] + bv1;
        }
    __syncthreads();

    #pragma unroll
    for (int s = 0; s < 8; ++s) {
        int idx = t + s * 256;
        int r = idx >> 5, c = (idx & 31) * 4;
        int gr = row0 + r;
        float4 o  = *(const float4*)&Cs[r * CSTF + c];
        float4 xo = make_float4(b2f(xpre[s].x), b2f(xpre[s].y),
                                b2f(xpre[s].z), b2f(xpre[s].w));
        o.x = g*o.x + gm*xo.x; o.y = g*o.y + gm*xo.y;
        o.z = g*o.z + gm*xo.z; o.w = g*o.w + gm*xo.w;
        st4(XS + (size_t)gr * 128 + c, o);
    }
}

// ---------------------------------------------------------------------------
// WCT[c][n*128+k] = (W @ blockdiag(rel))^T bf16;  BC[c] = b @ blockdiag(rel)
// c = 2*e + which (0=K, 1=V)
// ---------------------------------------------------------------------------
__global__ __launch_bounds__(256) void combine_kernel(
    const bf16* __restrict__ kw, const bf16* __restrict__ kb,
    const bf16* __restrict__ vw, const bf16* __restrict__ vb,
    const bf16* __restrict__ arel, const bf16* __restrict__ mrel,
    int l, bf16* __restrict__ WCT, float* __restrict__ BC)
{
    __shared__ float Rs[4096];
    int c = blockIdx.x;
    int e = c >> 1;
    int which = c & 1;
    int styp = (e == 0) ? 1 : 0;
    const bf16* W = (which ? vw : kw) + (size_t)(l*2 + styp) * (HID*HID);
    const bf16* B = (which ? vb : kb) + (size_t)(l*2 + styp) * HID;
    const bf16* R = (which ? mrel : arel) + (size_t)(l*3 + e) * (NHEAD*DHEAD*DHEAD);

    for (int s = threadIdx.x; s < 4096; s += 256) Rs[s] = b2f(R[s]);
    __syncthreads();

    int j = threadIdx.x & 127;
    int half = threadIdx.x >> 7;
    int h = j >> 5, jj = j & 31;
    const float* Rh = &Rs[h*1024 + jj];

    for (int k = half*64; k < half*64 + 64; ++k) {
        float sum = 0.f;
        #pragma unroll
        for (int dq = 0; dq < 8; ++dq) {
            float4 wv = ld4(W + k*HID + h*DHEAD + dq*4);
            sum += wv.x * Rh[(dq*4+0)*32] + wv.y * Rh[(dq*4+1)*32]
                 + wv.z * Rh[(dq*4+2)*32] + wv.w * Rh[(dq*4+3)*32];
        }
        WCT[(size_t)c*16384 + j*128 + k] = f2b(sum);
    }
    if (half == 0) {
        float sum = 0.f;
        #pragma unroll
        for (int dq = 0; dq < 8; ++dq) {
            float4 bv4 = ld4(B + h*DHEAD + dq*4);
            sum += bv4.x * Rh[(dq*4+0)*32] + bv4.y * Rh[(dq*4+1)*32]
                 + bv4.z * Rh[(dq*4+2)*32] + bv4.w * Rh[(dq*4+3)*32];
        }
        BC[c*128 + j] = sum;
    }
}

// ---------------------------------------------------------------------------
// CSR build
// ---------------------------------------------------------------------------
__global__ __launch_bounds__(256) void hist_kernel(
    const int* __restrict__ dst, int* __restrict__ cnt,
    int* __restrict__ rank, int nE)
{
    int i = blockIdx.x * 256 + threadIdx.x;
    if (i < nE) rank[i] = atomicAdd(&cnt[dst[i]], 1);
}

__global__ __launch_bounds__(256) void scan1_kernel(
    const int* __restrict__ cnt, int* __restrict__ off,
    int* __restrict__ bsum, int n)
{
    __shared__ int s[256];
    int i = blockIdx.x * 256 + threadIdx.x;
    int v = (i < n) ? cnt[i] : 0;
    s[threadIdx.x] = v; __syncthreads();
    for (int d = 1; d < 256; d <<= 1) {
        int t = (threadIdx.x >= d) ? s[threadIdx.x - d] : 0;
        __syncthreads();
        s[threadIdx.x] += t;
        __syncthreads();
    }
    if (i < n) off[i] = s[threadIdx.x] - v;
    if (threadIdx.x == 255) bsum[blockIdx.x] = s[255];
}

__global__ __launch_bounds__(512) void scan2_kernel(int* __restrict__ bsum, int nb)
{
    __shared__ int s[512];
    int v = (threadIdx.x < nb) ? bsum[threadIdx.x] : 0;
    s[threadIdx.x] = v; __syncthreads();
    for (int d = 1; d < 512; d <<= 1) {
        int t = (threadIdx.x >= d) ? s[threadIdx.x - d] : 0;
        __syncthreads();
        s[threadIdx.x] += t;
        __syncthreads();
    }
    if (threadIdx.x < nb) bsum[threadIdx.x] = s[threadIdx.x] - v;
}

__global__ __launch_bounds__(256) void scan3_kernel(
    int* __restrict__ off, const int* __restrict__ bsum, int n)
{
    int i = blockIdx.x * 256 + threadIdx.x;
    if (i < n) off[i] += bsum[blockIdx.x];
}

__global__ __launch_bounds__(256) void fill_kernel(
    const int* __restrict__ src, const int* __restrict__ dst,
    const int* __restrict__ off, const int* __restrict__ rank,
    int* __restrict__ csr, int nE, int srcoff)
{
    int i = blockIdx.x * 256 + threadIdx.x;
    if (i < nE) csr[off[dst[i]] + rank[i]] = src[i] + srcoff;
}

// ---------------------------------------------------------------------------
// Edge aggregation. KV interleaved: row s = [K(128) | V(128)] bf16.
// edge_fused: both paper-dst edge types (writes: rows pre-offset to author
// region; cites: paper rows), separate softmax each, single ACC write.
// edge_gather: single edge type (author dst).
// ---------------------------------------------------------------------------
__device__ __forceinline__ void edge_accum(
    const bf16* __restrict__ KV, const int* __restrict__ csr,
    int beg, int end, int j, float4 qv, float ph,
    float4& out)
{
    float4 num = make_float4(0.f, 0.f, 0.f, 0.f);
    float den = 0.f;
    for (int t = beg; t < end; ++t) {
        int s = csr[t];
        const bf16* row = KV + (size_t)s * 256;
        float4 kv = ld4(row + j*4);
        float4 vv = ld4(row + 128 + j*4);
        float p = qv.x*kv.x + qv.y*kv.y + qv.z*kv.z + qv.w*kv.w;
        p += __shfl_xor(p, 1);
        p += __shfl_xor(p, 2);
        p += __shfl_xor(p, 4);
        float ex = expf(p * ph);
        den += ex;
        num.x += ex*vv.x; num.y += ex*vv.y; num.z += ex*vv.z; num.w += ex*vv.w;
    }
    float inv = 1.f / (den + 1e-16f);
    out.x += num.x*inv; out.y += num.y*inv; out.z += num.z*inv; out.w += num.w*inv;
}

__global__ __launch_bounds__(256) void edge_fused(
    const bf16* __restrict__ Q, const bf16* __restrict__ KV,
    const int* __restrict__ off0, const int* __restrict__ csr0,
    const int* __restrict__ off2, const int* __restrict__ csr2,
    const bf16* __restrict__ prel0, const bf16* __restrict__ prel2,
    float* __restrict__ ACC, int Nd, int nE)
{
    int tid = blockIdx.x * 256 + threadIdx.x;
    int g = tid >> 5;
    if (g >= Nd) return;
    int j = tid & 31;
    float4 qv = ld4(Q + (size_t)g*128 + j*4);

    float4 r = make_float4(0.f, 0.f, 0.f, 0.f);
    {
        float ph = b2f(prel0[j >> 3]) * 0.17677669529663687f;
        int beg = off0[g];
        int end = (g == Nd - 1) ? nE : off0[g + 1];
        edge_accum(KV, csr0, beg, end, j, qv, ph, r);
    }
    {
        float ph = b2f(prel2[j >> 3]) * 0.17677669529663687f;
        int beg = off2[g];
        int end = (g == Nd - 1) ? nE : off2[g + 1];
        edge_accum(KV, csr2, beg, end, j, qv, ph, r);
    }
    *(float4*)&ACC[(size_t)g*128 + j*4] = r;
}

__global__ __launch_bounds__(256) void edge_gather(
    const bf16* __restrict__ Q, const bf16* __restrict__ KV,
    const int* __restrict__ off, const int* __restrict__ csr,
    const bf16* __restrict__ prel,
    float* __restrict__ ACC, int Nd, int nE)
{
    int tid = blockIdx.x * 256 + threadIdx.x;
    int g = tid >> 5;
    if (g >= Nd) return;
    int j = tid & 31;
    float4 qv = ld4(Q + (size_t)g*128 + j*4);
    float ph = b2f(prel[j >> 3]) * 0.17677669529663687f;

    float4 r = make_float4(0.f, 0.f, 0.f, 0.f);
    int beg = off[g];
    int end = (g == Nd - 1) ? nE : off[g + 1];
    edge_accum(KV, csr, beg, end, j, qv, ph, r);
    *(float4*)&ACC[(size_t)g*128 + j*4] = r;
}

// ---------------------------------------------------------------------------
__global__ __launch_bounds__(256) void gather_embed(
    const void* __restrict__ T, const int* __restrict__ idx,
    bf16* __restrict__ out, int n, const int* __restrict__ flag)
{
    int tid = blockIdx.x * 256 + threadIdx.x;
    int row = tid >> 4, c = tid & 15;
    if (row >= n) return;
    bool bf = flag[0] != 0;
    int srow = idx[row];
    bf16* o = out + (size_t)tid * 8;
    if (bf) {
        *(uint4*)o = ((const uint4*)T)[(size_t)srow*16 + c];
    } else {
        const float* s = (const float*)T + (size_t)srow*128 + c*8;
        float4 x = *(const float4*)s, y = *(const float4*)(s + 4);
        ((ushort4*)o)[0] = make_ushort4(f2b(x.x), f2b(x.y), f2b(x.z), f2b(x.w));
        ((ushort4*)o)[1] = make_ushort4(f2b(y.x), f2b(y.y), f2b(y.z), f2b(y.w));
    }
}

__global__ __launch_bounds__(256) void copy_out(
    const bf16* __restrict__ XS, void* __restrict__ out, int total8,
    const int* __restrict__ flag)
{
    int tid = blockIdx.x * 256 + threadIdx.x;
    if (tid >= total8) return;
    bool bf = flag[0] != 0;
    const int np8 = BATCH_PAPER * 16;
    const bf16* s = (tid < np8) ? (XS + (size_t)tid * 8)
                                : (XS + (size_t)NPAD * 128 + (size_t)(tid - np8) * 8);
    if (bf) {
        ((uint4*)out)[tid] = *(const uint4*)s;
    } else {
        float* o = (float*)out + (size_t)tid * 8;
        *(float4*)o = make_float4(b2f(s[0]), b2f(s[1]), b2f(s[2]), b2f(s[3]));
        *(float4*)(o + 4) = make_float4(b2f(s[4]), b2f(s[5]), b2f(s[6]), b2f(s[7]));
    }
}

// ---------------------------------------------------------------------------
extern "C" void kernel_launch(void* const* d_in, const int* in_sizes, int n_in,
                              void* d_out, int out_size, void* d_ws, size_t ws_size,
                              hipStream_t stream)
{
    const void* x_paper    = d_in[0];
    const int*  author_idx = (const int*)d_in[1];
    const void* embed      = d_in[2];
    const int* esrc[3] = { (const int*)d_in[17], (const int*)d_in[19], (const int*)d_in[21] };
    const int* edst[3] = { (const int*)d_in[18], (const int*)d_in[20], (const int*)d_in[22] };

    // workspace (256B-aligned carve-outs), ~210 MB total via liveness overlays:
    //   region R: Q-papers (dead after edge_fused) overlaid with ACC-authors
    //             (written by edge_gather, read by author epilogue)
    //   ACC-papers front: CSR-build scratch (rankb/cntb/bsumb, dead after build)
    uint8_t* p = (uint8_t*)d_ws;
    auto take = [&](size_t bytes) {
        uint8_t* q = p; p += (bytes + 255) & ~(size_t)255; return q;
    };
    bf16*  XS   = (bf16*) take((size_t)NTOT * HID * 2);   // papers | authors (padded)
    uint8_t* R  = take((size_t)NAPAD * HID * 4);          // max(Qp bf16, ACCa f32)
    bf16*  Qp   = (bf16*) R;                              // [NPAD x 128]
    float* ACCa = (float*)R;                              // [NAPAD x 128]
    bf16*  Qa   = (bf16*) take((size_t)NAPAD * HID * 2);
    bf16*  KV   = (bf16*) take((size_t)NTOT * 256 * 2);   // interleaved [K|V] rows
    float* ACCp = (float*)take((size_t)NPAD * HID * 4);
    bf16*  WCT  = (bf16*) take((size_t)6 * 16384 * 2);
    float* BC   = (float*)take((size_t)6 * 128 * 4);
    bf16*  WB   = (bf16*) take((size_t)O_WTOT * 2);
    bf16*  WTS  = (bf16*) take((size_t)9 * 16384 * 2);
    float* BF32 = (float*)take((size_t)9 * 128 * 4);
    int*   flag = (int*)  take(256);
    int Ndv[3] = { NPAPER, NAUTHOR, NPAPER };
    int* CSRoff[3];
    for (int e = 0; e < 3; ++e) CSRoff[e] = (int*)take((size_t)Ndv[e] * 4);
    int* CSRsrc[3];
    for (int e = 0; e < 3; ++e) CSRsrc[e] = (int*)take((size_t)NEDGE * 4);
    // CSR-build scratch overlaid on ACC-papers (dead once CSR built)
    int* rankb = (int*)ACCp;
    int* cntb  = rankb + NEDGE;
    int* bsumb = cntb + NPAPER;

    bf16* XSa = XS + (size_t)NPAD * HID;    // author region

    detect_kernel<<<1, 64, 0, stream>>>(d_in[13], flag);
    convert_weights<<<(O_WTOT + 255)/256, 256, 0, stream>>>(
        d_in[3], d_in[4], d_in[5], d_in[6], d_in[7], d_in[8], d_in[9], d_in[10],
        d_in[11], d_in[12], d_in[13], d_in[14], d_in[15], d_in[16], WB, flag);
    transpose_static<<<(9*16384 + 255)/256, 256, 0, stream>>>(WB, WTS);
    bias_prep<<<(9*128 + 255)/256, 256, 0, stream>>>(WB, BF32);

    // ---- CSR per edge type (e=0 srcs pre-offset into author KV region) ----
    const int EB = (NEDGE + 255) / 256;
    for (int e = 0; e < 3; ++e) {
        int Nd = Ndv[e];
        int nb = (Nd + 255) / 256;
        hipMemsetAsync(cntb, 0, (size_t)Nd * sizeof(int), stream);
        hist_kernel<<<EB, 256, 0, stream>>>(edst[e], cntb, rankb, NEDGE);
        scan1_kernel<<<nb, 256, 0, stream>>>(cntb, CSRoff[e], bsumb, Nd);
        scan2_kernel<<<1, 512, 0, stream>>>(bsumb, nb);
        scan3_kernel<<<nb, 256, 0, stream>>>(CSRoff[e], bsumb, Nd);
        fill_kernel<<<EB, 256, 0, stream>>>(esrc[e], edst[e], CSRoff[e], rankb,
                                            CSRsrc[e], NEDGE, (e == 0) ? NPAD : 0);
    }

    // ---- input projections ----
    gemm_proj<2,1><<<(NPAPER + 63)/64, 256, 0, stream>>>(
        x_paper, WTS, WTS, BF32, BF32, nullptr, nullptr, nullptr, nullptr,
        XS, nullptr, 128, NPAPER, NPAD, flag);
    gather_embed<<<(NAUTHOR*16 + 255)/256, 256, 0, stream>>>(embed, author_idx, XSa, NAUTHOR, flag);

    for (int l = 0; l < 2; ++l) {
        combine_kernel<<<6, 256, 0, stream>>>(WB + O_KW, WB + O_KB, WB + O_VW, WB + O_VB,
                                              WB + O_AREL, WB + O_MREL, l, WCT, BC);
        // Q projection, split (Qp and ACCa share a region -> non-contiguous Q)
        gemm_proj<0,1><<<NPAD/64, 256, 0, stream>>>(
            XS, WTS + (size_t)(1 + l*2)*16384, WTS + (size_t)(1 + l*2)*16384,
            BF32 + (1 + l*2)*128, BF32 + (1 + l*2)*128,
            nullptr, nullptr, nullptr, nullptr,
            Qp, nullptr, 128, NPAD, NPAD, flag);
        gemm_proj<0,1><<<NAPAD/64, 256, 0, stream>>>(
            XSa, WTS + (size_t)(2 + l*2)*16384, WTS + (size_t)(2 + l*2)*16384,
            BF32 + (2 + l*2)*128, BF32 + (2 + l*2)*128,
            nullptr, nullptr, nullptr, nullptr,
            Qa, nullptr, 128, NAPAD, NAPAD, flag);

        // K/V for paper-dst edges: papers get cites(e2) weights, authors get
        // writes(e0) weights; interleaved KV rows over all NTOT rows.
        gemm_proj<0,2><<<NTOT/64, 256, 0, stream>>>(
            XS,
            WCT + (size_t)4*16384, WCT + (size_t)0*16384,   // K
            BC + 4*128, BC + 0*128,
            WCT + (size_t)5*16384, WCT + (size_t)1*16384,   // V
            BC + 5*128, BC + 1*128,
            KV, KV + 128, 256,
            NTOT, NPAD, flag);

        // fused paper-dst aggregation: writes (author srcs, +NPAD rows) +
        // cites (paper srcs); separate softmax each; single ACC write.
        edge_fused<<<(NPAPER*32 + 255)/256, 256, 0, stream>>>(
            Qp, KV, CSRoff[0], CSRsrc[0], CSRoff[2], CSRsrc[2],
            WB + O_PREL + (l*3 + 0)*4, WB + O_PREL + (l*3 + 2)*4,
            ACCp, NPAPER, NEDGE);

        // K/V for author-dst edges (rev_writes e1, paper srcs): overwrite
        // paper rows of KV (fused kernel is done with them).
        gemm_proj<0,2><<<NPAD/64, 256, 0, stream>>>(
            XS,
            WCT + (size_t)2*16384, WCT + (size_t)2*16384,
            BC + 2*128, BC + 2*128,
            WCT + (size_t)3*16384, WCT + (size_t)3*16384,
            BC + 3*128, BC + 3*128,
            KV, KV + 128, 256,
            NPAD, NPAD + 64, flag);

        // author-dst aggregation; ACCa overwrites Qp region (Qp now dead)
        edge_gather<<<(NAUTHOR*32 + 255)/256, 256, 0, stream>>>(
            Qa, KV, CSRoff[1], CSRsrc[1],
            WB + O_PREL + (l*3 + 1)*4, ACCa, NAUTHOR, NEDGE);

        // fused epilogue, split (ACCp / ACCa non-contiguous)
        gemm_epi<<<NPAD/64, 256, 0, stream>>>(
            ACCp, WTS + (size_t)(5 + l*2)*16384, WTS + (size_t)(5 + l*2)*16384,
            BF32 + (5 + l*2)*128, BF32 + (5 + l*2)*128,
            WB + O_SKIP + l*2, XS, NPAD);
        gemm_epi<<<NAPAD/64, 256, 0, stream>>>(
            ACCa, WTS + (size_t)(6 + l*2)*16384, WTS + (size_t)(6 + l*2)*16384,
            BF32 + (6 + l*2)*128, BF32 + (6 + l*2)*128,
            WB + O_SKIP + l*2, XSa, 0);
    }

    int total8 = (BATCH_PAPER + BATCH_AUTHOR) * 16;
    copy_out<<<(total8 + 255)/256, 256, 0, stream>>>(XS, d_out, total8, flag);
}

// Round 5
// 724.404 us; speedup vs baseline: 1.1640x; 1.0271x over previous
//
#include <hip/hip_runtime.h>
#include <cstddef>
#include <cstdint>

#define HID     128
#define NHEAD   4
#define DHEAD   32
#define NPAPER  100000
#define NAUTHOR 50000
#define NEDGE   250000
#define BATCH_PAPER  50000
#define BATCH_AUTHOR 25000
#define NPAD    100032          // NPAPER padded to x64
#define NAPAD   50048           // NAUTHOR padded to x64
#define NTOT    150080          // NPAD + NAPAD

typedef unsigned short bf16;   // raw bf16 storage
typedef __attribute__((ext_vector_type(8))) short v8s;   // 8 bf16 (4 VGPRs)
typedef __attribute__((ext_vector_type(4))) float v4f;   // 4 fp32 acc

__device__ __forceinline__ float b2f(bf16 u) {
    union { unsigned int i; float f; } v; v.i = ((unsigned int)u) << 16; return v.f;
}
__device__ __forceinline__ bf16 f2b(float f) {
    unsigned int x = __float_as_uint(f);
    unsigned int r = x + 0x7fffu + ((x >> 16) & 1u);   // round-to-nearest-even
    return (bf16)(r >> 16);
}
__device__ __forceinline__ float4 ld4(const float* p) { return *(const float4*)p; }
__device__ __forceinline__ float4 ld4(const bf16* p) {
    ushort4 u = *(const ushort4*)p;
    return make_float4(b2f(u.x), b2f(u.y), b2f(u.z), b2f(u.w));
}
__device__ __forceinline__ void st4(float* p, float4 v) { *(float4*)p = v; }
__device__ __forceinline__ void st4(bf16* p, float4 v) {
    *(ushort4*)p = make_ushort4(f2b(v.x), f2b(v.y), f2b(v.z), f2b(v.w));
}
__device__ __forceinline__ float gelu_f(float x) {
    return 0.5f * x * (1.f + erff(x * 0.70710678118654752f));
}

// canonical bf16 weight-block element offsets
enum { O_LINW=0, O_LINB=16384, O_KW=16512, O_KB=82048, O_QW=82560, O_QB=148096,
       O_VW=148608, O_VB=214144, O_AREL=214656, O_MREL=239232, O_PREL=263808,
       O_SKIP=263832, O_AW=263836, O_AB=329372, O_WTOT=329884 };

// ---------------------------------------------------------------------------
__global__ void detect_kernel(const void* __restrict__ prel, int* __restrict__ flag)
{
    if (threadIdx.x == 0 && blockIdx.x == 0) {
        unsigned int w = *(const unsigned int*)prel;
        flag[0] = (w == 0x3F803F80u) ? 1 : 0;
    }
}

__global__ __launch_bounds__(256) void convert_weights(
    const void* lin_w, const void* lin_b, const void* k_w, const void* k_b,
    const void* q_w, const void* q_b, const void* v_w, const void* v_b,
    const void* a_rel, const void* m_rel, const void* p_rel, const void* skip,
    const void* a_w, const void* a_b,
    bf16* __restrict__ WB, const int* __restrict__ flag)
{
    int tid = blockIdx.x * 256 + threadIdx.x;
    if (tid >= O_WTOT) return;
    bool bf = flag[0] != 0;
    const void* src; int off = tid;
    if      (off < 16384)            { src = lin_w; }
    else if ((off -= 16384) < 128)   { src = lin_b; }
    else if ((off -= 128) < 65536)   { src = k_w; }
    else if ((off -= 65536) < 512)   { src = k_b; }
    else if ((off -= 512) < 65536)   { src = q_w; }
    else if ((off -= 65536) < 512)   { src = q_b; }
    else if ((off -= 512) < 65536)   { src = v_w; }
    else if ((off -= 65536) < 512)   { src = v_b; }
    else if ((off -= 512) < 24576)   { src = a_rel; }
    else if ((off -= 24576) < 24576) { src = m_rel; }
    else if ((off -= 24576) < 24)    { src = p_rel; }
    else if ((off -= 24) < 4)        { src = skip; }
    else if ((off -= 4) < 65536)     { src = a_w; }
    else                             { off -= 65536; src = a_b; }
    WB[tid] = bf ? ((const bf16*)src)[off] : f2b(((const float*)src)[off]);
}

// transpose the 9 static weights: WTS[m][n*128+k] = W_m[k*128+n]
// m: 0=lin_w, 1..4=q_w(l*2+t), 5..8=a_w(l*2+t)
__global__ __launch_bounds__(256) void transpose_static(
    const bf16* __restrict__ WB, bf16* __restrict__ WTS)
{
    int tid = blockIdx.x * 256 + threadIdx.x;
    if (tid >= 9 * 16384) return;
    int mtx = tid >> 14, idx = tid & 16383;
    int n = idx >> 7, k = idx & 127;
    int off = (mtx == 0) ? O_LINW
            : (mtx < 5)  ? O_QW + (mtx - 1) * 16384
                         : O_AW + (mtx - 5) * 16384;
    WTS[(size_t)mtx * 16384 + n * 128 + k] = WB[off + k * 128 + n];
}

__global__ __launch_bounds__(256) void bias_prep(
    const bf16* __restrict__ WB, float* __restrict__ BF32)
{
    int tid = blockIdx.x * 256 + threadIdx.x;
    if (tid >= 9 * 128) return;
    int m = tid >> 7, j = tid & 127;
    int off = (m == 0) ? O_LINB : (m < 5 ? O_QB + (m-1)*128 : O_AB + (m-5)*128);
    BF32[tid] = b2f(WB[off + j]);
}

// ---------------------------------------------------------------------------
// Fused MFMA projection GEMM, column-split waves + B-in-registers.
//   64-row tile, 256 thr = 4 waves; wave w owns output cols [w*32, w*32+32).
//   B fragments (8 x v8s = 32 VGPR) preloaded once per output pass ->
//   inner loop is LDS-only A-fragment reads + MFMA.
//   A staged in fragment-contiguous LDS layout (chunk d = [rb|ks|quad|m]).
//   C staged through LDS (bf16, bias pre-added) for 16B/lane coalesced
//   stores; diagonal remap (cc = (c8+r)&15) kills read conflicts.
//   Both passes select weights per block by row0<BND (a else b).
//   cstr: output row stride in elements (128 normal, 256 for interleaved KV).
// AMODE: 0 = A bf16, rows guaranteed padded (unguarded loads/stores)
//        2 = A dynamic dtype (d_in, flag), guarded by N
// ---------------------------------------------------------------------------
#define CSTB 136    // bf16 C-staging row stride (elements)
#define CSTF 132    // fp32 C-staging row stride (elements, gemm_epi)

template <int AMODE, int NOUT>
__global__ __launch_bounds__(256) void gemm_proj(
    const void* __restrict__ A,
    const bf16* __restrict__ WT0a, const bf16* __restrict__ WT0b,
    const float* __restrict__ b0a, const float* __restrict__ b0b,
    const bf16* __restrict__ WT1a, const bf16* __restrict__ WT1b,
    const float* __restrict__ b1a, const float* __restrict__ b1b,
    bf16* __restrict__ C0, bf16* __restrict__ C1, int cstr,
    int N, int BND, const int* __restrict__ flag)
{
    __shared__ __align__(16) bf16 As[64 * 128];   // 16 KB fragment-contiguous
    __shared__ __align__(16) bf16 Cs[64 * CSTB];  // 17.4 KB
    const int t = threadIdx.x;
    const int row0 = blockIdx.x * 64;
    const bool sela = row0 < BND;
    const bf16*  WT0 = sela ? WT0a : WT0b;
    const float* b0  = sela ? b0a  : b0b;

    // ---- stage A: chunk d holds A[row0 + rb*16+m][(ks*4+q)*8 .. +8) ----
    if (AMODE == 0) {
        #pragma unroll
        for (int s = 0; s < 4; ++s) {
            int d = t + s * 256;
            int m_ = d & 15, q_ = (d >> 4) & 3, ks_ = (d >> 6) & 3, rb_ = d >> 8;
            int gr = row0 + rb_ * 16 + m_;
            *(uint4*)&As[d * 8] =
                *(const uint4*)((const bf16*)A + (size_t)gr * 128 + (ks_ * 4 + q_) * 8);
        }
    } else {
        bool a_bf = flag[0] != 0;
        #pragma unroll
        for (int s = 0; s < 4; ++s) {
            int d = t + s * 256;
            int m_ = d & 15, q_ = (d >> 4) & 3, ks_ = (d >> 6) & 3, rb_ = d >> 8;
            int gr = row0 + rb_ * 16 + m_;
            int c8 = ks_ * 4 + q_;
            bf16* dst = &As[d * 8];
            if (gr < N) {
                if (a_bf) {
                    *(uint4*)dst = *(const uint4*)((const bf16*)A + (size_t)gr * 128 + c8 * 8);
                } else {
                    const float* ap = (const float*)A + (size_t)gr * 128 + c8 * 8;
                    float4 x = *(const float4*)ap, y = *(const float4*)(ap + 4);
                    ((ushort4*)dst)[0] = make_ushort4(f2b(x.x), f2b(x.y), f2b(x.z), f2b(x.w));
                    ((ushort4*)dst)[1] = make_ushort4(f2b(y.x), f2b(y.y), f2b(y.z), f2b(y.w));
                }
            } else {
                *(uint4*)dst = make_uint4(0, 0, 0, 0);
            }
        }
    }
    __syncthreads();

    const int lane = t & 63;
    const int wave = t >> 6;
    const int m    = lane & 15;
    const int quad = lane >> 4;
    const int colbase = wave * 32;

    auto pass = [&](const bf16* __restrict__ WT, const float* __restrict__ bias,
                    bf16* __restrict__ C, bool needBar) {
        float bv0 = bias[colbase + m];
        float bv1 = bias[colbase + 16 + m];
        v8s bfrag[2][4];
        #pragma unroll
        for (int c2 = 0; c2 < 2; ++c2)
            #pragma unroll
            for (int ks = 0; ks < 4; ++ks)
                bfrag[c2][ks] = *(const v8s*)&WT[
                    (size_t)(colbase + c2 * 16 + m) * 128 + ks * 32 + quad * 8];
        if (needBar) __syncthreads();           // pass-1 copy-out readers done

        #pragma unroll
        for (int rb = 0; rb < 4; ++rb) {
            v4f a0 = (v4f){0.f, 0.f, 0.f, 0.f};
            v4f a1 = (v4f){0.f, 0.f, 0.f, 0.f};
            #pragma unroll
            for (int ks = 0; ks < 4; ++ks) {
                v8s av = *(const v8s*)&As[(((rb * 4 + ks) << 6) + lane) * 8];
                a0 = __builtin_amdgcn_mfma_f32_16x16x32_bf16(av, bfrag[0][ks], a0, 0, 0, 0);
                a1 = __builtin_amdgcn_mfma_f32_16x16x32_bf16(av, bfrag[1][ks], a1, 0, 0, 0);
            }
            #pragma unroll
            for (int rg = 0; rg < 4; ++rg) {
                int row = rb * 16 + quad * 4 + rg;
                Cs[row * CSTB + colbase + m]      = f2b(a0[rg] + bv0);
                Cs[row * CSTB + colbase + 16 + m] = f2b(a1[rg] + bv1);
            }
        }
        __syncthreads();
        #pragma unroll
        for (int s = 0; s < 4; ++s) {
            int idx = t + s * 256;
            int r = idx >> 4, c8 = idx & 15;
            int cc = (c8 + r) & 15;             // diagonal: conflict-free Cs reads
            int gr = row0 + r;
            if (AMODE == 0 || gr < N)
                *(uint4*)(C + (size_t)gr * cstr + cc * 8) =
                    *(const uint4*)&Cs[r * CSTB + cc * 8];
        }
    };

    pass(WT0, b0, C0, false);
    if (NOUT == 2) {
        const bf16*  WT1 = sela ? WT1a : WT1b;
        const float* b1  = sela ? b1a  : b1b;
        pass(WT1, b1, C1, true);
    }
}

// ---------------------------------------------------------------------------
// Fused epilogue GEMM: XS = g*(gelu(scale*ACC)@W^T + b) + (1-g)*XS
// 64-row tile, column-split B-in-registers; fp32 C staging (aliasing As to
// keep LDS at 33.8 KB -> 4 blocks/CU) preserves skip-blend numerics exactly.
// XS skip rows prefetched to registers during staging. In-place on XS.
// ---------------------------------------------------------------------------
__global__ __launch_bounds__(256) void gemm_epi(
    const float* __restrict__ ACC,
    const bf16* __restrict__ WTa, const bf16* __restrict__ WTb,
    const float* __restrict__ ba, const float* __restrict__ bb,
    const bf16* __restrict__ skv,     // [0]=paper gate, [1]=author gate
    bf16* __restrict__ XS, int BND)
{
    __shared__ __align__(16) float Cs[64 * CSTF];  // 33.8 KB; As aliases front
    bf16* As = (bf16*)Cs;                          // 64*128*2 = 16 KB
    const int t = threadIdx.x;
    const int row0 = blockIdx.x * 64;
    bool paper = row0 < BND;
    const bf16*  WT   = paper ? WTa : WTb;
    const float* bias = paper ? ba : bb;
    float scale = paper ? 0.5f : 1.0f;      // mean over {2,1} edge types
    float sv = b2f(paper ? skv[0] : skv[1]);
    float g = 1.f / (1.f + expf(-sv)), gm = 1.f - g;

    #pragma unroll
    for (int s = 0; s < 4; ++s) {            // stage gelu(scale*ACC) as bf16
        int d = t + s * 256;
        int m_ = d & 15, q_ = (d >> 4) & 3, ks_ = (d >> 6) & 3, rb_ = d >> 8;
        int gr = row0 + rb_ * 16 + m_;
        const float* ap = ACC + (size_t)gr * 128 + (ks_ * 4 + q_) * 8;
        float4 x = *(const float4*)ap, y = *(const float4*)(ap + 4);
        x.x = gelu_f(scale*x.x); x.y = gelu_f(scale*x.y);
        x.z = gelu_f(scale*x.z); x.w = gelu_f(scale*x.w);
        y.x = gelu_f(scale*y.x); y.y = gelu_f(scale*y.y);
        y.z = gelu_f(scale*y.z); y.w = gelu_f(scale*y.w);
        bf16* dst = &As[d * 8];
        ((ushort4*)dst)[0] = make_ushort4(f2b(x.x), f2b(x.y), f2b(x.z), f2b(x.w));
        ((ushort4*)dst)[1] = make_ushort4(f2b(y.x), f2b(y.y), f2b(y.z), f2b(y.w));
    }

    // prefetch skip-input XS rows (registers; latency hides under MFMA)
    ushort4 xpre[8];
    #pragma unroll
    for (int s = 0; s < 8; ++s) {
        int idx = t + s * 256;
        int r = idx >> 5, c = (idx & 31) * 4;
        xpre[s] = *(const ushort4*)(XS + (size_t)(row0 + r) * 128 + c);
    }

    const int lane = t & 63;
    const int wave = t >> 6;
    const int m    = lane & 15;
    const int quad = lane >> 4;
    const int colbase = wave * 32;

    float bv0 = bias[colbase + m];
    float bv1 = bias[colbase + 16 + m];
    v8s bfrag[2][4];
    #pragma unroll
    for (int c2 = 0; c2 < 2; ++c2)
        #pragma unroll
        for (int ks = 0; ks < 4; ++ks)
            bfrag[c2][ks] = *(const v8s*)&WT[
                (size_t)(colbase + c2 * 16 + m) * 128 + ks * 32 + quad * 8];
    __syncthreads();                               // As staged

    v4f acc[4][2];
    #pragma unroll
    for (int rb = 0; rb < 4; ++rb) {
        v4f a0 = (v4f){0.f, 0.f, 0.f, 0.f};
        v4f a1 = (v4f){0.f, 0.f, 0.f, 0.f};
        #pragma unroll
        for (int ks = 0; ks < 4; ++ks) {
            v8s av = *(const v8s*)&As[(((rb * 4 + ks) << 6) + lane) * 8];
            a0 = __builtin_amdgcn_mfma_f32_16x16x32_bf16(av, bfrag[0][ks], a0, 0, 0, 0);
            a1 = __builtin_amdgcn_mfma_f32_16x16x32_bf16(av, bfrag[1][ks], a1, 0, 0, 0);
        }
        acc[rb][0] = a0; acc[rb][1] = a1;
    }
    __syncthreads();                               // all As reads done (alias!)

    #pragma unroll
    for (int rb = 0; rb < 4; ++rb)
        #pragma unroll
        for (int rg = 0; rg < 4; ++rg) {
            int row = rb * 16 + quad * 4 + rg;
            Cs[row * CSTF + colbase + m]      = acc[rb][0][rg] + bv0;
            Cs[row * CSTF + colbase + 16 + m] = acc[rb][1][rg] + bv1;
        }
    __syncthreads();

    #pragma unroll
    for (int s = 0; s < 8; ++s) {
        int idx = t + s * 256;
        int r = idx >> 5, c = (idx & 31) * 4;
        int gr = row0 + r;
        float4 o  = *(const float4*)&Cs[r * CSTF + c];
        float4 xo = make_float4(b2f(xpre[s].x), b2f(xpre[s].y),
                                b2f(xpre[s].z), b2f(xpre[s].w));
        o.x = g*o.x + gm*xo.x; o.y = g*o.y + gm*xo.y;
        o.z = g*o.z + gm*xo.z; o.w = g*o.w + gm*xo.w;
        st4(XS + (size_t)gr * 128 + c, o);
    }
}

// ---------------------------------------------------------------------------
// WCT[c][n*128+k] = (W @ blockdiag(rel))^T bf16;  BC[c] = b @ blockdiag(rel)
// c = 2*e + which (0=K, 1=V)
// ---------------------------------------------------------------------------
__global__ __launch_bounds__(256) void combine_kernel(
    const bf16* __restrict__ kw, const bf16* __restrict__ kb,
    const bf16* __restrict__ vw, const bf16* __restrict__ vb,
    const bf16* __restrict__ arel, const bf16* __restrict__ mrel,
    int l, bf16* __restrict__ WCT, float* __restrict__ BC)
{
    __shared__ float Rs[4096];
    int c = blockIdx.x;
    int e = c >> 1;
    int which = c & 1;
    int styp = (e == 0) ? 1 : 0;
    const bf16* W = (which ? vw : kw) + (size_t)(l*2 + styp) * (HID*HID);
    const bf16* B = (which ? vb : kb) + (size_t)(l*2 + styp) * HID;
    const bf16* R = (which ? mrel : arel) + (size_t)(l*3 + e) * (NHEAD*DHEAD*DHEAD);

    for (int s = threadIdx.x; s < 4096; s += 256) Rs[s] = b2f(R[s]);
    __syncthreads();

    int j = threadIdx.x & 127;
    int half = threadIdx.x >> 7;
    int h = j >> 5, jj = j & 31;
    const float* Rh = &Rs[h*1024 + jj];

    for (int k = half*64; k < half*64 + 64; ++k) {
        float sum = 0.f;
        #pragma unroll
        for (int dq = 0; dq < 8; ++dq) {
            float4 wv = ld4(W + k*HID + h*DHEAD + dq*4);
            sum += wv.x * Rh[(dq*4+0)*32] + wv.y * Rh[(dq*4+1)*32]
                 + wv.z * Rh[(dq*4+2)*32] + wv.w * Rh[(dq*4+3)*32];
        }
        WCT[(size_t)c*16384 + j*128 + k] = f2b(sum);
    }
    if (half == 0) {
        float sum = 0.f;
        #pragma unroll
        for (int dq = 0; dq < 8; ++dq) {
            float4 bv4 = ld4(B + h*DHEAD + dq*4);
            sum += bv4.x * Rh[(dq*4+0)*32] + bv4.y * Rh[(dq*4+1)*32]
                 + bv4.z * Rh[(dq*4+2)*32] + bv4.w * Rh[(dq*4+3)*32];
        }
        BC[c*128 + j] = sum;
    }
}

// ---------------------------------------------------------------------------
// CSR build
// ---------------------------------------------------------------------------
__global__ __launch_bounds__(256) void hist_kernel(
    const int* __restrict__ dst, int* __restrict__ cnt,
    int* __restrict__ rank, int nE)
{
    int i = blockIdx.x * 256 + threadIdx.x;
    if (i < nE) rank[i] = atomicAdd(&cnt[dst[i]], 1);
}

__global__ __launch_bounds__(256) void scan1_kernel(
    const int* __restrict__ cnt, int* __restrict__ off,
    int* __restrict__ bsum, int n)
{
    __shared__ int s[256];
    int i = blockIdx.x * 256 + threadIdx.x;
    int v = (i < n) ? cnt[i] : 0;
    s[threadIdx.x] = v; __syncthreads();
    for (int d = 1; d < 256; d <<= 1) {
        int t = (threadIdx.x >= d) ? s[threadIdx.x - d] : 0;
        __syncthreads();
        s[threadIdx.x] += t;
        __syncthreads();
    }
    if (i < n) off[i] = s[threadIdx.x] - v;
    if (threadIdx.x == 255) bsum[blockIdx.x] = s[255];
}

__global__ __launch_bounds__(512) void scan2_kernel(int* __restrict__ bsum, int nb)
{
    __shared__ int s[512];
    int v = (threadIdx.x < nb) ? bsum[threadIdx.x] : 0;
    s[threadIdx.x] = v; __syncthreads();
    for (int d = 1; d < 512; d <<= 1) {
        int t = (threadIdx.x >= d) ? s[threadIdx.x - d] : 0;
        __syncthreads();
        s[threadIdx.x] += t;
        __syncthreads();
    }
    if (threadIdx.x < nb) bsum[threadIdx.x] = s[threadIdx.x] - v;
}

__global__ __launch_bounds__(256) void scan3_kernel(
    int* __restrict__ off, const int* __restrict__ bsum, int n)
{
    int i = blockIdx.x * 256 + threadIdx.x;
    if (i < n) off[i] += bsum[blockIdx.x];
}

__global__ __launch_bounds__(256) void fill_kernel(
    const int* __restrict__ src, const int* __restrict__ dst,
    const int* __restrict__ off, const int* __restrict__ rank,
    int* __restrict__ csr, int nE, int srcoff)
{
    int i = blockIdx.x * 256 + threadIdx.x;
    if (i < nE) csr[off[dst[i]] + rank[i]] = src[i] + srcoff;
}

// ---------------------------------------------------------------------------
// Edge aggregation. KV interleaved: row s = [K(128) | V(128)] bf16.
// edge_accum: pair-unrolled edge walk — loads for edges t,t+1 issue together
// (2x memory-level parallelism) but accumulation happens in ORIGINAL
// sequential order (den += e0; num += e0*v0; den += e1; ...) -> bitwise-
// identical to the non-unrolled loop.
// edge_fused: both paper-dst edge types (writes: rows pre-offset to author
// region; cites: paper rows), separate softmax each, single ACC write.
// edge_gather: single edge type (author dst).
// ---------------------------------------------------------------------------
__device__ __forceinline__ void edge_accum(
    const bf16* __restrict__ KV, const int* __restrict__ csr,
    int beg, int end, int j, float4 qv, float ph,
    float4& out)
{
    float4 num = make_float4(0.f, 0.f, 0.f, 0.f);
    float den = 0.f;
    int t = beg;
    for (; t + 2 <= end; t += 2) {
        int s0 = csr[t];
        int s1 = csr[t + 1];
        const bf16* r0 = KV + (size_t)s0 * 256;
        const bf16* r1 = KV + (size_t)s1 * 256;
        float4 k0 = ld4(r0 + j*4);
        float4 v0 = ld4(r0 + 128 + j*4);
        float4 k1 = ld4(r1 + j*4);
        float4 v1 = ld4(r1 + 128 + j*4);
        float p0 = qv.x*k0.x + qv.y*k0.y + qv.z*k0.z + qv.w*k0.w;
        float p1 = qv.x*k1.x + qv.y*k1.y + qv.z*k1.z + qv.w*k1.w;
        p0 += __shfl_xor(p0, 1);  p1 += __shfl_xor(p1, 1);
        p0 += __shfl_xor(p0, 2);  p1 += __shfl_xor(p1, 2);
        p0 += __shfl_xor(p0, 4);  p1 += __shfl_xor(p1, 4);
        float e0 = expf(p0 * ph);
        float e1 = expf(p1 * ph);
        den += e0;
        num.x += e0*v0.x; num.y += e0*v0.y; num.z += e0*v0.z; num.w += e0*v0.w;
        den += e1;
        num.x += e1*v1.x; num.y += e1*v1.y; num.z += e1*v1.z; num.w += e1*v1.w;
    }
    if (t < end) {
        int s = csr[t];
        const bf16* row = KV + (size_t)s * 256;
        float4 kv = ld4(row + j*4);
        float4 vv = ld4(row + 128 + j*4);
        float p = qv.x*kv.x + qv.y*kv.y + qv.z*kv.z + qv.w*kv.w;
        p += __shfl_xor(p, 1);
        p += __shfl_xor(p, 2);
        p += __shfl_xor(p, 4);
        float ex = expf(p * ph);
        den += ex;
        num.x += ex*vv.x; num.y += ex*vv.y; num.z += ex*vv.z; num.w += ex*vv.w;
    }
    float inv = 1.f / (den + 1e-16f);
    out.x += num.x*inv; out.y += num.y*inv; out.z += num.z*inv; out.w += num.w*inv;
}

__global__ __launch_bounds__(256) void edge_fused(
    const bf16* __restrict__ Q, const bf16* __restrict__ KV,
    const int* __restrict__ off0, const int* __restrict__ csr0,
    const int* __restrict__ off2, const int* __restrict__ csr2,
    const bf16* __restrict__ prel0, const bf16* __restrict__ prel2,
    float* __restrict__ ACC, int Nd, int nE)
{
    int tid = blockIdx.x * 256 + threadIdx.x;
    int g = tid >> 5;
    if (g >= Nd) return;
    int j = tid & 31;
    float4 qv = ld4(Q + (size_t)g*128 + j*4);

    float4 r = make_float4(0.f, 0.f, 0.f, 0.f);
    {
        float ph = b2f(prel0[j >> 3]) * 0.17677669529663687f;
        int beg = off0[g];
        int end = (g == Nd - 1) ? nE : off0[g + 1];
        edge_accum(KV, csr0, beg, end, j, qv, ph, r);
    }
    {
        float ph = b2f(prel2[j >> 3]) * 0.17677669529663687f;
        int beg = off2[g];
        int end = (g == Nd - 1) ? nE : off2[g + 1];
        edge_accum(KV, csr2, beg, end, j, qv, ph, r);
    }
    *(float4*)&ACC[(size_t)g*128 + j*4] = r;
}

__global__ __launch_bounds__(256) void edge_gather(
    const bf16* __restrict__ Q, const bf16* __restrict__ KV,
    const int* __restrict__ off, const int* __restrict__ csr,
    const bf16* __restrict__ prel,
    float* __restrict__ ACC, int Nd, int nE)
{
    int tid = blockIdx.x * 256 + threadIdx.x;
    int g = tid >> 5;
    if (g >= Nd) return;
    int j = tid & 31;
    float4 qv = ld4(Q + (size_t)g*128 + j*4);
    float ph = b2f(prel[j >> 3]) * 0.17677669529663687f;

    float4 r = make_float4(0.f, 0.f, 0.f, 0.f);
    int beg = off[g];
    int end = (g == Nd - 1) ? nE : off[g + 1];
    edge_accum(KV, csr, beg, end, j, qv, ph, r);
    *(float4*)&ACC[(size_t)g*128 + j*4] = r;
}

// ---------------------------------------------------------------------------
__global__ __launch_bounds__(256) void gather_embed(
    const void* __restrict__ T, const int* __restrict__ idx,
    bf16* __restrict__ out, int n, const int* __restrict__ flag)
{
    int tid = blockIdx.x * 256 + threadIdx.x;
    int row = tid >> 4, c = tid & 15;
    if (row >= n) return;
    bool bf = flag[0] != 0;
    int srow = idx[row];
    bf16* o = out + (size_t)tid * 8;
    if (bf) {
        *(uint4*)o = ((const uint4*)T)[(size_t)srow*16 + c];
    } else {
        const float* s = (const float*)T + (size_t)srow*128 + c*8;
        float4 x = *(const float4*)s, y = *(const float4*)(s + 4);
        ((ushort4*)o)[0] = make_ushort4(f2b(x.x), f2b(x.y), f2b(x.z), f2b(x.w));
        ((ushort4*)o)[1] = make_ushort4(f2b(y.x), f2b(y.y), f2b(y.z), f2b(y.w));
    }
}

__global__ __launch_bounds__(256) void copy_out(
    const bf16* __restrict__ XS, void* __restrict__ out, int total8,
    const int* __restrict__ flag)
{
    int tid = blockIdx.x * 256 + threadIdx.x;
    if (tid >= total8) return;
    bool bf = flag[0] != 0;
    const int np8 = BATCH_PAPER * 16;
    const bf16* s = (tid < np8) ? (XS + (size_t)tid * 8)
                                : (XS + (size_t)NPAD * 128 + (size_t)(tid - np8) * 8);
    if (bf) {
        ((uint4*)out)[tid] = *(const uint4*)s;
    } else {
        float* o = (float*)out + (size_t)tid * 8;
        *(float4*)o = make_float4(b2f(s[0]), b2f(s[1]), b2f(s[2]), b2f(s[3]));
        *(float4*)(o + 4) = make_float4(b2f(s[4]), b2f(s[5]), b2f(s[6]), b2f(s[7]));
    }
}

// ---------------------------------------------------------------------------
extern "C" void kernel_launch(void* const* d_in, const int* in_sizes, int n_in,
                              void* d_out, int out_size, void* d_ws, size_t ws_size,
                              hipStream_t stream)
{
    const void* x_paper    = d_in[0];
    const int*  author_idx = (const int*)d_in[1];
    const void* embed      = d_in[2];
    const int* esrc[3] = { (const int*)d_in[17], (const int*)d_in[19], (const int*)d_in[21] };
    const int* edst[3] = { (const int*)d_in[18], (const int*)d_in[20], (const int*)d_in[22] };

    // workspace (256B-aligned carve-outs), ~210 MB total via liveness overlays:
    //   region R: Q-papers (dead after edge_fused) overlaid with ACC-authors
    //             (written by edge_gather, read by author epilogue)
    //   ACC-papers front: CSR-build scratch (rankb/cntb/bsumb, dead after build)
    uint8_t* p = (uint8_t*)d_ws;
    auto take = [&](size_t bytes) {
        uint8_t* q = p; p += (bytes + 255) & ~(size_t)255; return q;
    };
    bf16*  XS   = (bf16*) take((size_t)NTOT * HID * 2);   // papers | authors (padded)
    uint8_t* R  = take((size_t)NAPAD * HID * 4);          // max(Qp bf16, ACCa f32)
    bf16*  Qp   = (bf16*) R;                              // [NPAD x 128]
    float* ACCa = (float*)R;                              // [NAPAD x 128]
    bf16*  Qa   = (bf16*) take((size_t)NAPAD * HID * 2);
    bf16*  KV   = (bf16*) take((size_t)NTOT * 256 * 2);   // interleaved [K|V] rows
    float* ACCp = (float*)take((size_t)NPAD * HID * 4);
    bf16*  WCT  = (bf16*) take((size_t)6 * 16384 * 2);
    float* BC   = (float*)take((size_t)6 * 128 * 4);
    bf16*  WB   = (bf16*) take((size_t)O_WTOT * 2);
    bf16*  WTS  = (bf16*) take((size_t)9 * 16384 * 2);
    float* BF32 = (float*)take((size_t)9 * 128 * 4);
    int*   flag = (int*)  take(256);
    int Ndv[3] = { NPAPER, NAUTHOR, NPAPER };
    int* CSRoff[3];
    for (int e = 0; e < 3; ++e) CSRoff[e] = (int*)take((size_t)Ndv[e] * 4);
    int* CSRsrc[3];
    for (int e = 0; e < 3; ++e) CSRsrc[e] = (int*)take((size_t)NEDGE * 4);
    // CSR-build scratch overlaid on ACC-papers (dead once CSR built)
    int* rankb = (int*)ACCp;
    int* cntb  = rankb + NEDGE;
    int* bsumb = cntb + NPAPER;

    bf16* XSa = XS + (size_t)NPAD * HID;    // author region

    detect_kernel<<<1, 64, 0, stream>>>(d_in[13], flag);
    convert_weights<<<(O_WTOT + 255)/256, 256, 0, stream>>>(
        d_in[3], d_in[4], d_in[5], d_in[6], d_in[7], d_in[8], d_in[9], d_in[10],
        d_in[11], d_in[12], d_in[13], d_in[14], d_in[15], d_in[16], WB, flag);
    transpose_static<<<(9*16384 + 255)/256, 256, 0, stream>>>(WB, WTS);
    bias_prep<<<(9*128 + 255)/256, 256, 0, stream>>>(WB, BF32);

    // ---- CSR per edge type (e=0 srcs pre-offset into author KV region) ----
    const int EB = (NEDGE + 255) / 256;
    for (int e = 0; e < 3; ++e) {
        int Nd = Ndv[e];
        int nb = (Nd + 255) / 256;
        hipMemsetAsync(cntb, 0, (size_t)Nd * sizeof(int), stream);
        hist_kernel<<<EB, 256, 0, stream>>>(edst[e], cntb, rankb, NEDGE);
        scan1_kernel<<<nb, 256, 0, stream>>>(cntb, CSRoff[e], bsumb, Nd);
        scan2_kernel<<<1, 512, 0, stream>>>(bsumb, nb);
        scan3_kernel<<<nb, 256, 0, stream>>>(CSRoff[e], bsumb, Nd);
        fill_kernel<<<EB, 256, 0, stream>>>(esrc[e], edst[e], CSRoff[e], rankb,
                                            CSRsrc[e], NEDGE, (e == 0) ? NPAD : 0);
    }

    // ---- input projections ----
    gemm_proj<2,1><<<(NPAPER + 63)/64, 256, 0, stream>>>(
        x_paper, WTS, WTS, BF32, BF32, nullptr, nullptr, nullptr, nullptr,
        XS, nullptr, 128, NPAPER, NPAD, flag);
    gather_embed<<<(NAUTHOR*16 + 255)/256, 256, 0, stream>>>(embed, author_idx, XSa, NAUTHOR, flag);

    for (int l = 0; l < 2; ++l) {
        combine_kernel<<<6, 256, 0, stream>>>(WB + O_KW, WB + O_KB, WB + O_VW, WB + O_VB,
                                              WB + O_AREL, WB + O_MREL, l, WCT, BC);
        // Q projection, split (Qp and ACCa share a region -> non-contiguous Q)
        gemm_proj<0,1><<<NPAD/64, 256, 0, stream>>>(
            XS, WTS + (size_t)(1 + l*2)*16384, WTS + (size_t)(1 + l*2)*16384,
            BF32 + (1 + l*2)*128, BF32 + (1 + l*2)*128,
            nullptr, nullptr, nullptr, nullptr,
            Qp, nullptr, 128, NPAD, NPAD, flag);
        gemm_proj<0,1><<<NAPAD/64, 256, 0, stream>>>(
            XSa, WTS + (size_t)(2 + l*2)*16384, WTS + (size_t)(2 + l*2)*16384,
            BF32 + (2 + l*2)*128, BF32 + (2 + l*2)*128,
            nullptr, nullptr, nullptr, nullptr,
            Qa, nullptr, 128, NAPAD, NAPAD, flag);

        // K/V for paper-dst edges: papers get cites(e2) weights, authors get
        // writes(e0) weights; interleaved KV rows over all NTOT rows.
        gemm_proj<0,2><<<NTOT/64, 256, 0, stream>>>(
            XS,
            WCT + (size_t)4*16384, WCT + (size_t)0*16384,   // K
            BC + 4*128, BC + 0*128,
            WCT + (size_t)5*16384, WCT + (size_t)1*16384,   // V
            BC + 5*128, BC + 1*128,
            KV, KV + 128, 256,
            NTOT, NPAD, flag);

        // fused paper-dst aggregation: writes (author srcs, +NPAD rows) +
        // cites (paper srcs); separate softmax each; single ACC write.
        edge_fused<<<(NPAPER*32 + 255)/256, 256, 0, stream>>>(
            Qp, KV, CSRoff[0], CSRsrc[0], CSRoff[2], CSRsrc[2],
            WB + O_PREL + (l*3 + 0)*4, WB + O_PREL + (l*3 + 2)*4,
            ACCp, NPAPER, NEDGE);

        // K/V for author-dst edges (rev_writes e1, paper srcs): overwrite
        // paper rows of KV (fused kernel is done with them).
        gemm_proj<0,2><<<NPAD/64, 256, 0, stream>>>(
            XS,
            WCT + (size_t)2*16384, WCT + (size_t)2*16384,
            BC + 2*128, BC + 2*128,
            WCT + (size_t)3*16384, WCT + (size_t)3*16384,
            BC + 3*128, BC + 3*128,
            KV, KV + 128, 256,
            NPAD, NPAD + 64, flag);

        // author-dst aggregation; ACCa overwrites Qp region (Qp now dead)
        edge_gather<<<(NAUTHOR*32 + 255)/256, 256, 0, stream>>>(
            Qa, KV, CSRoff[1], CSRsrc[1],
            WB + O_PREL + (l*3 + 1)*4, ACCa, NAUTHOR, NEDGE);

        // fused epilogue, split (ACCp / ACCa non-contiguous)
        gemm_epi<<<NPAD/64, 256, 0, stream>>>(
            ACCp, WTS + (size_t)(5 + l*2)*16384, WTS + (size_t)(5 + l*2)*16384,
            BF32 + (5 + l*2)*128, BF32 + (5 + l*2)*128,
            WB + O_SKIP + l*2, XS, NPAD);
        gemm_epi<<<NAPAD/64, 256, 0, stream>>>(
            ACCa, WTS + (size_t)(6 + l*2)*16384, WTS + (size_t)(6 + l*2)*16384,
            BF32 + (6 + l*2)*128, BF32 + (6 + l*2)*128,
            WB + O_SKIP + l*2, XSa, 0);
    }

    int total8 = (BATCH_PAPER + BATCH_AUTHOR) * 16;
    copy_out<<<(total8 + 255)/256, 256, 0, stream>>>(XS, d_out, total8, flag);
}

// Round 7
// 716.505 us; speedup vs baseline: 1.1768x; 1.0110x over previous
//
#include <hip/hip_runtime.h>
#include <cstddef>
#include <cstdint>

#define HID     128
#define NHEAD   4
#define DHEAD   32
#define NPAPER  100000
#define NAUTHOR 50000
#define NEDGE   250000
#define BATCH_PAPER  50000
#define BATCH_AUTHOR 25000
#define NPAD    100032          // NPAPER padded to x64
#define NAPAD   50048           // NAUTHOR padded to x64
#define NTOT    150080          // NPAD + NAPAD

typedef unsigned short bf16;   // raw bf16 storage
typedef __attribute__((ext_vector_type(8))) short v8s;   // 8 bf16 (4 VGPRs)
typedef __attribute__((ext_vector_type(4))) float v4f;   // 4 fp32 acc

__device__ __forceinline__ float b2f(bf16 u) {
    union { unsigned int i; float f; } v; v.i = ((unsigned int)u) << 16; return v.f;
}
__device__ __forceinline__ bf16 f2b(float f) {
    unsigned int x = __float_as_uint(f);
    unsigned int r = x + 0x7fffu + ((x >> 16) & 1u);   // round-to-nearest-even
    return (bf16)(r >> 16);
}
__device__ __forceinline__ float4 ld4(const float* p) { return *(const float4*)p; }
__device__ __forceinline__ float4 ld4(const bf16* p) {
    ushort4 u = *(const ushort4*)p;
    return make_float4(b2f(u.x), b2f(u.y), b2f(u.z), b2f(u.w));
}
__device__ __forceinline__ void st4(float* p, float4 v) { *(float4*)p = v; }
__device__ __forceinline__ void st4(bf16* p, float4 v) {
    *(ushort4*)p = make_ushort4(f2b(v.x), f2b(v.y), f2b(v.z), f2b(v.w));
}
__device__ __forceinline__ float gelu_f(float x) {
    return 0.5f * x * (1.f + erff(x * 0.70710678118654752f));
}

// canonical bf16 weight-block element offsets
enum { O_LINW=0, O_LINB=16384, O_KW=16512, O_KB=82048, O_QW=82560, O_QB=148096,
       O_VW=148608, O_VB=214144, O_AREL=214656, O_MREL=239232, O_PREL=263808,
       O_SKIP=263832, O_AW=263836, O_AB=329372, O_WTOT=329884 };

// ---------------------------------------------------------------------------
__global__ void detect_kernel(const void* __restrict__ prel, int* __restrict__ flag)
{
    if (threadIdx.x == 0 && blockIdx.x == 0) {
        unsigned int w = *(const unsigned int*)prel;
        flag[0] = (w == 0x3F803F80u) ? 1 : 0;
    }
}

__global__ __launch_bounds__(256) void convert_weights(
    const void* lin_w, const void* lin_b, const void* k_w, const void* k_b,
    const void* q_w, const void* q_b, const void* v_w, const void* v_b,
    const void* a_rel, const void* m_rel, const void* p_rel, const void* skip,
    const void* a_w, const void* a_b,
    bf16* __restrict__ WB, const int* __restrict__ flag)
{
    int tid = blockIdx.x * 256 + threadIdx.x;
    if (tid >= O_WTOT) return;
    bool bf = flag[0] != 0;
    const void* src; int off = tid;
    if      (off < 16384)            { src = lin_w; }
    else if ((off -= 16384) < 128)   { src = lin_b; }
    else if ((off -= 128) < 65536)   { src = k_w; }
    else if ((off -= 65536) < 512)   { src = k_b; }
    else if ((off -= 512) < 65536)   { src = q_w; }
    else if ((off -= 65536) < 512)   { src = q_b; }
    else if ((off -= 512) < 65536)   { src = v_w; }
    else if ((off -= 65536) < 512)   { src = v_b; }
    else if ((off -= 512) < 24576)   { src = a_rel; }
    else if ((off -= 24576) < 24576) { src = m_rel; }
    else if ((off -= 24576) < 24)    { src = p_rel; }
    else if ((off -= 24) < 4)        { src = skip; }
    else if ((off -= 4) < 65536)     { src = a_w; }
    else                             { off -= 65536; src = a_b; }
    WB[tid] = bf ? ((const bf16*)src)[off] : f2b(((const float*)src)[off]);
}

// transpose the 9 static weights: WTS[m][n*128+k] = W_m[k*128+n]
// m: 0=lin_w, 1..4=q_w(l*2+t), 5..8=a_w(l*2+t)
__global__ __launch_bounds__(256) void transpose_static(
    const bf16* __restrict__ WB, bf16* __restrict__ WTS)
{
    int tid = blockIdx.x * 256 + threadIdx.x;
    if (tid >= 9 * 16384) return;
    int mtx = tid >> 14, idx = tid & 16383;
    int n = idx >> 7, k = idx & 127;
    int off = (mtx == 0) ? O_LINW
            : (mtx < 5)  ? O_QW + (mtx - 1) * 16384
                         : O_AW + (mtx - 5) * 16384;
    WTS[(size_t)mtx * 16384 + n * 128 + k] = WB[off + k * 128 + n];
}

__global__ __launch_bounds__(256) void bias_prep(
    const bf16* __restrict__ WB, float* __restrict__ BF32)
{
    int tid = blockIdx.x * 256 + threadIdx.x;
    if (tid >= 9 * 128) return;
    int m = tid >> 7, j = tid & 127;
    int off = (m == 0) ? O_LINB : (m < 5 ? O_QB + (m-1)*128 : O_AB + (m-5)*128);
    BF32[tid] = b2f(WB[off + j]);
}

// ---------------------------------------------------------------------------
// Fused MFMA projection GEMM, column-split waves + B-in-registers.
//   64-row tile, 256 thr = 4 waves; wave w owns output cols [w*32, w*32+32).
//   B fragments (8 x v8s = 32 VGPR) preloaded once per output pass ->
//   inner loop is LDS-only A-fragment reads + MFMA.
//   A staged in fragment-contiguous LDS layout (chunk d = [rb|ks|quad|m]).
//   C staged through LDS (bf16, bias pre-added) for 16B/lane coalesced
//   stores; diagonal remap (cc = (c8+r)&15) kills read conflicts.
//   Both passes select weights per block by row0<BND (a else b).
//   cstr: output row stride in elements (128 normal, 256 for interleaved KV).
// AMODE: 0 = A bf16, rows guaranteed padded (unguarded loads/stores)
//        2 = A dynamic dtype (d_in, flag), guarded by N
// ---------------------------------------------------------------------------
#define CSTB 136    // bf16 C-staging row stride (elements)
#define CSTF 132    // fp32 C-staging row stride (elements, gemm_epi)

template <int AMODE, int NOUT>
__global__ __launch_bounds__(256) void gemm_proj(
    const void* __restrict__ A,
    const bf16* __restrict__ WT0a, const bf16* __restrict__ WT0b,
    const float* __restrict__ b0a, const float* __restrict__ b0b,
    const bf16* __restrict__ WT1a, const bf16* __restrict__ WT1b,
    const float* __restrict__ b1a, const float* __restrict__ b1b,
    bf16* __restrict__ C0, bf16* __restrict__ C1, int cstr,
    int N, int BND, const int* __restrict__ flag)
{
    __shared__ __align__(16) bf16 As[64 * 128];   // 16 KB fragment-contiguous
    __shared__ __align__(16) bf16 Cs[64 * CSTB];  // 17.4 KB
    const int t = threadIdx.x;
    const int row0 = blockIdx.x * 64;
    const bool sela = row0 < BND;
    const bf16*  WT0 = sela ? WT0a : WT0b;
    const float* b0  = sela ? b0a  : b0b;

    // ---- stage A: chunk d holds A[row0 + rb*16+m][(ks*4+q)*8 .. +8) ----
    if (AMODE == 0) {
        #pragma unroll
        for (int s = 0; s < 4; ++s) {
            int d = t + s * 256;
            int m_ = d & 15, q_ = (d >> 4) & 3, ks_ = (d >> 6) & 3, rb_ = d >> 8;
            int gr = row0 + rb_ * 16 + m_;
            *(uint4*)&As[d * 8] =
                *(const uint4*)((const bf16*)A + (size_t)gr * 128 + (ks_ * 4 + q_) * 8);
        }
    } else {
        bool a_bf = flag[0] != 0;
        #pragma unroll
        for (int s = 0; s < 4; ++s) {
            int d = t + s * 256;
            int m_ = d & 15, q_ = (d >> 4) & 3, ks_ = (d >> 6) & 3, rb_ = d >> 8;
            int gr = row0 + rb_ * 16 + m_;
            int c8 = ks_ * 4 + q_;
            bf16* dst = &As[d * 8];
            if (gr < N) {
                if (a_bf) {
                    *(uint4*)dst = *(const uint4*)((const bf16*)A + (size_t)gr * 128 + c8 * 8);
                } else {
                    const float* ap = (const float*)A + (size_t)gr * 128 + c8 * 8;
                    float4 x = *(const float4*)ap, y = *(const float4*)(ap + 4);
                    ((ushort4*)dst)[0] = make_ushort4(f2b(x.x), f2b(x.y), f2b(x.z), f2b(x.w));
                    ((ushort4*)dst)[1] = make_ushort4(f2b(y.x), f2b(y.y), f2b(y.z), f2b(y.w));
                }
            } else {
                *(uint4*)dst = make_uint4(0, 0, 0, 0);
            }
        }
    }
    __syncthreads();

    const int lane = t & 63;
    const int wave = t >> 6;
    const int m    = lane & 15;
    const int quad = lane >> 4;
    const int colbase = wave * 32;

    auto pass = [&](const bf16* __restrict__ WT, const float* __restrict__ bias,
                    bf16* __restrict__ C, bool needBar) {
        float bv0 = bias[colbase + m];
        float bv1 = bias[colbase + 16 + m];
        v8s bfrag[2][4];
        #pragma unroll
        for (int c2 = 0; c2 < 2; ++c2)
            #pragma unroll
            for (int ks = 0; ks < 4; ++ks)
                bfrag[c2][ks] = *(const v8s*)&WT[
                    (size_t)(colbase + c2 * 16 + m) * 128 + ks * 32 + quad * 8];
        if (needBar) __syncthreads();           // pass-1 copy-out readers done

        #pragma unroll
        for (int rb = 0; rb < 4; ++rb) {
            v4f a0 = (v4f){0.f, 0.f, 0.f, 0.f};
            v4f a1 = (v4f){0.f, 0.f, 0.f, 0.f};
            #pragma unroll
            for (int ks = 0; ks < 4; ++ks) {
                v8s av = *(const v8s*)&As[(((rb * 4 + ks) << 6) + lane) * 8];
                a0 = __builtin_amdgcn_mfma_f32_16x16x32_bf16(av, bfrag[0][ks], a0, 0, 0, 0);
                a1 = __builtin_amdgcn_mfma_f32_16x16x32_bf16(av, bfrag[1][ks], a1, 0, 0, 0);
            }
            #pragma unroll
            for (int rg = 0; rg < 4; ++rg) {
                int row = rb * 16 + quad * 4 + rg;
                Cs[row * CSTB + colbase + m]      = f2b(a0[rg] + bv0);
                Cs[row * CSTB + colbase + 16 + m] = f2b(a1[rg] + bv1);
            }
        }
        __syncthreads();
        #pragma unroll
        for (int s = 0; s < 4; ++s) {
            int idx = t + s * 256;
            int r = idx >> 4, c8 = idx & 15;
            int cc = (c8 + r) & 15;             // diagonal: conflict-free Cs reads
            int gr = row0 + r;
            if (AMODE == 0 || gr < N)
                *(uint4*)(C + (size_t)gr * cstr + cc * 8) =
                    *(const uint4*)&Cs[r * CSTB + cc * 8];
        }
    };

    pass(WT0, b0, C0, false);
    if (NOUT == 2) {
        const bf16*  WT1 = sela ? WT1a : WT1b;
        const float* b1  = sela ? b1a  : b1b;
        pass(WT1, b1, C1, true);
    }
}

// ---------------------------------------------------------------------------
// Fused epilogue GEMM: XS = g*(gelu(scale*ACC)@W^T + b) + (1-g)*XS
// 64-row tile, column-split B-in-registers; fp32 C staging (aliasing As to
// keep LDS at 33.8 KB -> 4 blocks/CU) preserves skip-blend numerics exactly.
// XS skip rows prefetched to registers during staging. In-place on XS.
// ---------------------------------------------------------------------------
__global__ __launch_bounds__(256) void gemm_epi(
    const float* __restrict__ ACC,
    const bf16* __restrict__ WTa, const bf16* __restrict__ WTb,
    const float* __restrict__ ba, const float* __restrict__ bb,
    const bf16* __restrict__ skv,     // [0]=paper gate, [1]=author gate
    bf16* __restrict__ XS, int BND)
{
    __shared__ __align__(16) float Cs[64 * CSTF];  // 33.8 KB; As aliases front
    bf16* As = (bf16*)Cs;                          // 64*128*2 = 16 KB
    const int t = threadIdx.x;
    const int row0 = blockIdx.x * 64;
    bool paper = row0 < BND;
    const bf16*  WT   = paper ? WTa : WTb;
    const float* bias = paper ? ba : bb;
    float scale = paper ? 0.5f : 1.0f;      // mean over {2,1} edge types
    float sv = b2f(paper ? skv[0] : skv[1]);
    float g = 1.f / (1.f + expf(-sv)), gm = 1.f - g;

    #pragma unroll
    for (int s = 0; s < 4; ++s) {            // stage gelu(scale*ACC) as bf16
        int d = t + s * 256;
        int m_ = d & 15, q_ = (d >> 4) & 3, ks_ = (d >> 6) & 3, rb_ = d >> 8;
        int gr = row0 + rb_ * 16 + m_;
        const float* ap = ACC + (size_t)gr * 128 + (ks_ * 4 + q_) * 8;
        float4 x = *(const float4*)ap, y = *(const float4*)(ap + 4);
        x.x = gelu_f(scale*x.x); x.y = gelu_f(scale*x.y);
        x.z = gelu_f(scale*x.z); x.w = gelu_f(scale*x.w);
        y.x = gelu_f(scale*y.x); y.y = gelu_f(scale*y.y);
        y.z = gelu_f(scale*y.z); y.w = gelu_f(scale*y.w);
        bf16* dst = &As[d * 8];
        ((ushort4*)dst)[0] = make_ushort4(f2b(x.x), f2b(x.y), f2b(x.z), f2b(x.w));
        ((ushort4*)dst)[1] = make_ushort4(f2b(y.x), f2b(y.y), f2b(y.z), f2b(y.w));
    }

    // prefetch skip-input XS rows (registers; latency hides under MFMA)
    ushort4 xpre[8];
    #pragma unroll
    for (int s = 0; s < 8; ++s) {
        int idx = t + s * 256;
        int r = idx >> 5, c = (idx & 31) * 4;
        xpre[s] = *(const ushort4*)(XS + (size_t)(row0 + r) * 128 + c);
    }

    const int lane = t & 63;
    const int wave = t >> 6;
    const int m    = lane & 15;
    const int quad = lane >> 4;
    const int colbase = wave * 32;

    float bv0 = bias[colbase + m];
    float bv1 = bias[colbase + 16 + m];
    v8s bfrag[2][4];
    #pragma unroll
    for (int c2 = 0; c2 < 2; ++c2)
        #pragma unroll
        for (int ks = 0; ks < 4; ++ks)
            bfrag[c2][ks] = *(const v8s*)&WT[
                (size_t)(colbase + c2 * 16 + m) * 128 + ks * 32 + quad * 8];
    __syncthreads();                               // As staged

    v4f acc[4][2];
    #pragma unroll
    for (int rb = 0; rb < 4; ++rb) {
        v4f a0 = (v4f){0.f, 0.f, 0.f, 0.f};
        v4f a1 = (v4f){0.f, 0.f, 0.f, 0.f};
        #pragma unroll
        for (int ks = 0; ks < 4; ++ks) {
            v8s av = *(const v8s*)&As[(((rb * 4 + ks) << 6) + lane) * 8];
            a0 = __builtin_amdgcn_mfma_f32_16x16x32_bf16(av, bfrag[0][ks], a0, 0, 0, 0);
            a1 = __builtin_amdgcn_mfma_f32_16x16x32_bf16(av, bfrag[1][ks], a1, 0, 0, 0);
        }
        acc[rb][0] = a0; acc[rb][1] = a1;
    }
    __syncthreads();                               // all As reads done (alias!)

    #pragma unroll
    for (int rb = 0; rb < 4; ++rb)
        #pragma unroll
        for (int rg = 0; rg < 4; ++rg) {
            int row = rb * 16 + quad * 4 + rg;
            Cs[row * CSTF + colbase + m]      = acc[rb][0][rg] + bv0;
            Cs[row * CSTF + colbase + 16 + m] = acc[rb][1][rg] + bv1;
        }
    __syncthreads();

    #pragma unroll
    for (int s = 0; s < 8; ++s) {
        int idx = t + s * 256;
        int r = idx >> 5, c = (idx & 31) * 4;
        int gr = row0 + r;
        float4 o  = *(const float4*)&Cs[r * CSTF + c];
        float4 xo = make_float4(b2f(xpre[s].x), b2f(xpre[s].y),
                                b2f(xpre[s].z), b2f(xpre[s].w));
        o.x = g*o.x + gm*xo.x; o.y = g*o.y + gm*xo.y;
        o.z = g*o.z + gm*xo.z; o.w = g*o.w + gm*xo.w;
        st4(XS + (size_t)gr * 128 + c, o);
    }
}

// ---------------------------------------------------------------------------
// WCT[c][n*128+k] = (W @ blockdiag(rel))^T bf16;  BC[c] = b @ blockdiag(rel)
// c = 2*e + which (0=K, 1=V)
// ---------------------------------------------------------------------------
__global__ __launch_bounds__(256) void combine_kernel(
    const bf16* __restrict__ kw, const bf16* __restrict__ kb,
    const bf16* __restrict__ vw, const bf16* __restrict__ vb,
    const bf16* __restrict__ arel, const bf16* __restrict__ mrel,
    int l, bf16* __restrict__ WCT, float* __restrict__ BC)
{
    __shared__ float Rs[4096];
    int c = blockIdx.x;
    int e = c >> 1;
    int which = c & 1;
    int styp = (e == 0) ? 1 : 0;
    const bf16* W = (which ? vw : kw) + (size_t)(l*2 + styp) * (HID*HID);
    const bf16* B = (which ? vb : kb) + (size_t)(l*2 + styp) * HID;
    const bf16* R = (which ? mrel : arel) + (size_t)(l*3 + e) * (NHEAD*DHEAD*DHEAD);

    for (int s = threadIdx.x; s < 4096; s += 256) Rs[s] = b2f(R[s]);
    __syncthreads();

    int j = threadIdx.x & 127;
    int half = threadIdx.x >> 7;
    int h = j >> 5, jj = j & 31;
    const float* Rh = &Rs[h*1024 + jj];

    for (int k = half*64; k < half*64 + 64; ++k) {
        float sum = 0.f;
        #pragma unroll
        for (int dq = 0; dq < 8; ++dq) {
            float4 wv = ld4(W + k*HID + h*DHEAD + dq*4);
            sum += wv.x * Rh[(dq*4+0)*32] + wv.y * Rh[(dq*4+1)*32]
                 + wv.z * Rh[(dq*4+2)*32] + wv.w * Rh[(dq*4+3)*32];
        }
        WCT[(size_t)c*16384 + j*128 + k] = f2b(sum);
    }
    if (half == 0) {
        float sum = 0.f;
        #pragma unroll
        for (int dq = 0; dq < 8; ++dq) {
            float4 bv4 = ld4(B + h*DHEAD + dq*4);
            sum += bv4.x * Rh[(dq*4+0)*32] + bv4.y * Rh[(dq*4+1)*32]
                 + bv4.z * Rh[(dq*4+2)*32] + bv4.w * Rh[(dq*4+3)*32];
        }
        BC[c*128 + j] = sum;
    }
}

// ---------------------------------------------------------------------------
// CSR build
// ---------------------------------------------------------------------------
__global__ __launch_bounds__(256) void hist_kernel(
    const int* __restrict__ dst, int* __restrict__ cnt,
    int* __restrict__ rank, int nE)
{
    int i = blockIdx.x * 256 + threadIdx.x;
    if (i < nE) rank[i] = atomicAdd(&cnt[dst[i]], 1);
}

__global__ __launch_bounds__(256) void scan1_kernel(
    const int* __restrict__ cnt, int* __restrict__ off,
    int* __restrict__ bsum, int n)
{
    __shared__ int s[256];
    int i = blockIdx.x * 256 + threadIdx.x;
    int v = (i < n) ? cnt[i] : 0;
    s[threadIdx.x] = v; __syncthreads();
    for (int d = 1; d < 256; d <<= 1) {
        int t = (threadIdx.x >= d) ? s[threadIdx.x - d] : 0;
        __syncthreads();
        s[threadIdx.x] += t;
        __syncthreads();
    }
    if (i < n) off[i] = s[threadIdx.x] - v;
    if (threadIdx.x == 255) bsum[blockIdx.x] = s[255];
}

__global__ __launch_bounds__(512) void scan2_kernel(int* __restrict__ bsum, int nb)
{
    __shared__ int s[512];
    int v = (threadIdx.x < nb) ? bsum[threadIdx.x] : 0;
    s[threadIdx.x] = v; __syncthreads();
    for (int d = 1; d < 512; d <<= 1) {
        int t = (threadIdx.x >= d) ? s[threadIdx.x - d] : 0;
        __syncthreads();
        s[threadIdx.x] += t;
        __syncthreads();
    }
    if (threadIdx.x < nb) bsum[threadIdx.x] = s[threadIdx.x] - v;
}

__global__ __launch_bounds__(256) void scan3_kernel(
    int* __restrict__ off, const int* __restrict__ bsum, int n)
{
    int i = blockIdx.x * 256 + threadIdx.x;
    if (i < n) off[i] += bsum[blockIdx.x];
}

__global__ __launch_bounds__(256) void fill_kernel(
    const int* __restrict__ src, const int* __restrict__ dst,
    const int* __restrict__ off, const int* __restrict__ rank,
    int* __restrict__ csr, int nE, int srcoff)
{
    int i = blockIdx.x * 256 + threadIdx.x;
    if (i < nE) csr[off[dst[i]] + rank[i]] = src[i] + srcoff;
}

// ---------------------------------------------------------------------------
// Edge aggregation. KV interleaved: row s = [K(128) | V(128)] bf16.
// Within each CSR walk, edges are ALWAYS accumulated in index order ->
// bitwise-identical to a plain sequential loop; unrolling/interleaving only
// raises the number of independent load/dot/exp chains in flight.
// __expf (hw v_exp_f32): softmax-weight perturbation ~1e-6 rel, invisible
// under the existing bf16 rounding error.
// ---------------------------------------------------------------------------
__device__ __forceinline__ float edot(float4 a, float4 b) {
    return a.x*b.x + a.y*b.y + a.z*b.z + a.w*b.w;
}
__device__ __forceinline__ float hred(float p) {
    p += __shfl_xor(p, 1);
    p += __shfl_xor(p, 2);
    p += __shfl_xor(p, 4);
    return p;
}

// pair-unrolled remainder of a walk (order-preserving)
__device__ __forceinline__ void edge_walk_tail(
    const bf16* __restrict__ KV, const int* __restrict__ csr,
    int t, int end, int j, float4 qv, float ph,
    float4& num, float& den)
{
    for (; t + 2 <= end; t += 2) {
        int s0 = csr[t];
        int s1 = csr[t + 1];
        const bf16* r0 = KV + (size_t)s0 * 256;
        const bf16* r1 = KV + (size_t)s1 * 256;
        float4 k0 = ld4(r0 + j*4);
        float4 v0 = ld4(r0 + 128 + j*4);
        float4 k1 = ld4(r1 + j*4);
        float4 v1 = ld4(r1 + 128 + j*4);
        float p0 = hred(edot(qv, k0));
        float p1 = hred(edot(qv, k1));
        float e0 = __expf(p0 * ph);
        float e1 = __expf(p1 * ph);
        den += e0;
        num.x += e0*v0.x; num.y += e0*v0.y; num.z += e0*v0.z; num.w += e0*v0.w;
        den += e1;
        num.x += e1*v1.x; num.y += e1*v1.y; num.z += e1*v1.z; num.w += e1*v1.w;
    }
    if (t < end) {
        int s = csr[t];
        const bf16* row = KV + (size_t)s * 256;
        float4 kv = ld4(row + j*4);
        float4 vv = ld4(row + 128 + j*4);
        float p = hred(edot(qv, kv));
        float ex = __expf(p * ph);
        den += ex;
        num.x += ex*vv.x; num.y += ex*vv.y; num.z += ex*vv.z; num.w += ex*vv.w;
    }
}

// both paper-dst edge types, walks interleaved (2+2 then 1+1 then tails)
__global__ __launch_bounds__(256) void edge_fused(
    const bf16* __restrict__ Q, const bf16* __restrict__ KV,
    const int* __restrict__ off0, const int* __restrict__ csr0,
    const int* __restrict__ off2, const int* __restrict__ csr2,
    const bf16* __restrict__ prel0, const bf16* __restrict__ prel2,
    float* __restrict__ ACC, int Nd, int nE)
{
    int tid = blockIdx.x * 256 + threadIdx.x;
    int g = tid >> 5;
    if (g >= Nd) return;
    int j = tid & 31;
    float4 qv = ld4(Q + (size_t)g*128 + j*4);
    float phA = b2f(prel0[j >> 3]) * 0.17677669529663687f;
    float phB = b2f(prel2[j >> 3]) * 0.17677669529663687f;

    int tA = off0[g], endA = (g == Nd - 1) ? nE : off0[g + 1];
    int tB = off2[g], endB = (g == Nd - 1) ? nE : off2[g + 1];
    float4 numA = make_float4(0.f, 0.f, 0.f, 0.f);
    float4 numB = make_float4(0.f, 0.f, 0.f, 0.f);
    float denA = 0.f, denB = 0.f;

    // 2 from each walk: 4 independent chains
    while (tA + 2 <= endA && tB + 2 <= endB) {
        int a0 = csr0[tA], a1 = csr0[tA + 1];
        int b0 = csr2[tB], b1 = csr2[tB + 1];
        const bf16* ra0 = KV + (size_t)a0 * 256;
        const bf16* ra1 = KV + (size_t)a1 * 256;
        const bf16* rb0 = KV + (size_t)b0 * 256;
        const bf16* rb1 = KV + (size_t)b1 * 256;
        float4 ka0 = ld4(ra0 + j*4), va0 = ld4(ra0 + 128 + j*4);
        float4 ka1 = ld4(ra1 + j*4), va1 = ld4(ra1 + 128 + j*4);
        float4 kb0 = ld4(rb0 + j*4), vb0 = ld4(rb0 + 128 + j*4);
        float4 kb1 = ld4(rb1 + j*4), vb1 = ld4(rb1 + 128 + j*4);
        float pa0 = hred(edot(qv, ka0));
        float pa1 = hred(edot(qv, ka1));
        float pb0 = hred(edot(qv, kb0));
        float pb1 = hred(edot(qv, kb1));
        float ea0 = __expf(pa0 * phA);
        float ea1 = __expf(pa1 * phA);
        float eb0 = __expf(pb0 * phB);
        float eb1 = __expf(pb1 * phB);
        denA += ea0;
        numA.x += ea0*va0.x; numA.y += ea0*va0.y; numA.z += ea0*va0.z; numA.w += ea0*va0.w;
        denA += ea1;
        numA.x += ea1*va1.x; numA.y += ea1*va1.y; numA.z += ea1*va1.z; numA.w += ea1*va1.w;
        denB += eb0;
        numB.x += eb0*vb0.x; numB.y += eb0*vb0.y; numB.z += eb0*vb0.z; numB.w += eb0*vb0.w;
        denB += eb1;
        numB.x += eb1*vb1.x; numB.y += eb1*vb1.y; numB.z += eb1*vb1.z; numB.w += eb1*vb1.w;
        tA += 2; tB += 2;
    }
    // 1 from each walk: 2 chains
    while (tA < endA && tB < endB) {
        int a0 = csr0[tA];
        int b0 = csr2[tB];
        const bf16* ra0 = KV + (size_t)a0 * 256;
        const bf16* rb0 = KV + (size_t)b0 * 256;
        float4 ka0 = ld4(ra0 + j*4), va0 = ld4(ra0 + 128 + j*4);
        float4 kb0 = ld4(rb0 + j*4), vb0 = ld4(rb0 + 128 + j*4);
        float pa0 = hred(edot(qv, ka0));
        float pb0 = hred(edot(qv, kb0));
        float ea0 = __expf(pa0 * phA);
        float eb0 = __expf(pb0 * phB);
        denA += ea0;
        numA.x += ea0*va0.x; numA.y += ea0*va0.y; numA.z += ea0*va0.z; numA.w += ea0*va0.w;
        denB += eb0;
        numB.x += eb0*vb0.x; numB.y += eb0*vb0.y; numB.z += eb0*vb0.z; numB.w += eb0*vb0.w;
        ++tA; ++tB;
    }
    edge_walk_tail(KV, csr0, tA, endA, j, qv, phA, numA, denA);
    edge_walk_tail(KV, csr2, tB, endB, j, qv, phB, numB, denB);

    float invA = 1.f / (denA + 1e-16f);
    float invB = 1.f / (denB + 1e-16f);
    float4 r;
    r.x = numA.x*invA + numB.x*invB;
    r.y = numA.y*invA + numB.y*invB;
    r.z = numA.z*invA + numB.z*invB;
    r.w = numA.w*invA + numB.w*invB;
    *(float4*)&ACC[(size_t)g*128 + j*4] = r;
}

// single edge type (author dst, avg degree 5): 4-unrolled walk
__global__ __launch_bounds__(256) void edge_gather(
    const bf16* __restrict__ Q, const bf16* __restrict__ KV,
    const int* __restrict__ off, const int* __restrict__ csr,
    const bf16* __restrict__ prel,
    float* __restrict__ ACC, int Nd, int nE)
{
    int tid = blockIdx.x * 256 + threadIdx.x;
    int g = tid >> 5;
    if (g >= Nd) return;
    int j = tid & 31;
    float4 qv = ld4(Q + (size_t)g*128 + j*4);
    float ph = b2f(prel[j >> 3]) * 0.17677669529663687f;

    int t = off[g];
    int end = (g == Nd - 1) ? nE : off[g + 1];
    float4 num = make_float4(0.f, 0.f, 0.f, 0.f);
    float den = 0.f;

    for (; t + 4 <= end; t += 4) {
        int s0 = csr[t],     s1 = csr[t + 1];
        int s2 = csr[t + 2], s3 = csr[t + 3];
        const bf16* r0 = KV + (size_t)s0 * 256;
        const bf16* r1 = KV + (size_t)s1 * 256;
        const bf16* r2 = KV + (size_t)s2 * 256;
        const bf16* r3 = KV + (size_t)s3 * 256;
        float4 k0 = ld4(r0 + j*4), v0 = ld4(r0 + 128 + j*4);
        float4 k1 = ld4(r1 + j*4), v1 = ld4(r1 + 128 + j*4);
        float4 k2 = ld4(r2 + j*4), v2 = ld4(r2 + 128 + j*4);
        float4 k3 = ld4(r3 + j*4), v3 = ld4(r3 + 128 + j*4);
        float p0 = hred(edot(qv, k0));
        float p1 = hred(edot(qv, k1));
        float p2 = hred(edot(qv, k2));
        float p3 = hred(edot(qv, k3));
        float e0 = __expf(p0 * ph);
        float e1 = __expf(p1 * ph);
        float e2 = __expf(p2 * ph);
        float e3 = __expf(p3 * ph);
        den += e0;
        num.x += e0*v0.x; num.y += e0*v0.y; num.z += e0*v0.z; num.w += e0*v0.w;
        den += e1;
        num.x += e1*v1.x; num.y += e1*v1.y; num.z += e1*v1.z; num.w += e1*v1.w;
        den += e2;
        num.x += e2*v2.x; num.y += e2*v2.y; num.z += e2*v2.z; num.w += e2*v2.w;
        den += e3;
        num.x += e3*v3.x; num.y += e3*v3.y; num.z += e3*v3.z; num.w += e3*v3.w;
    }
    edge_walk_tail(KV, csr, t, end, j, qv, ph, num, den);

    float inv = 1.f / (den + 1e-16f);
    float4 r = make_float4(num.x*inv, num.y*inv, num.z*inv, num.w*inv);
    *(float4*)&ACC[(size_t)g*128 + j*4] = r;
}

// ---------------------------------------------------------------------------
__global__ __launch_bounds__(256) void gather_embed(
    const void* __restrict__ T, const int* __restrict__ idx,
    bf16* __restrict__ out, int n, const int* __restrict__ flag)
{
    int tid = blockIdx.x * 256 + threadIdx.x;
    int row = tid >> 4, c = tid & 15;
    if (row >= n) return;
    bool bf = flag[0] != 0;
    int srow = idx[row];
    bf16* o = out + (size_t)tid * 8;
    if (bf) {
        *(uint4*)o = ((const uint4*)T)[(size_t)srow*16 + c];
    } else {
        const float* s = (const float*)T + (size_t)srow*128 + c*8;
        float4 x = *(const float4*)s, y = *(const float4*)(s + 4);
        ((ushort4*)o)[0] = make_ushort4(f2b(x.x), f2b(x.y), f2b(x.z), f2b(x.w));
        ((ushort4*)o)[1] = make_ushort4(f2b(y.x), f2b(y.y), f2b(y.z), f2b(y.w));
    }
}

__global__ __launch_bounds__(256) void copy_out(
    const bf16* __restrict__ XS, void* __restrict__ out, int total8,
    const int* __restrict__ flag)
{
    int tid = blockIdx.x * 256 + threadIdx.x;
    if (tid >= total8) return;
    bool bf = flag[0] != 0;
    const int np8 = BATCH_PAPER * 16;
    const bf16* s = (tid < np8) ? (XS + (size_t)tid * 8)
                                : (XS + (size_t)NPAD * 128 + (size_t)(tid - np8) * 8);
    if (bf) {
        ((uint4*)out)[tid] = *(const uint4*)s;
    } else {
        float* o = (float*)out + (size_t)tid * 8;
        *(float4*)o = make_float4(b2f(s[0]), b2f(s[1]), b2f(s[2]), b2f(s[3]));
        *(float4*)(o + 4) = make_float4(b2f(s[4]), b2f(s[5]), b2f(s[6]), b2f(s[7]));
    }
}

// ---------------------------------------------------------------------------
extern "C" void kernel_launch(void* const* d_in, const int* in_sizes, int n_in,
                              void* d_out, int out_size, void* d_ws, size_t ws_size,
                              hipStream_t stream)
{
    const void* x_paper    = d_in[0];
    const int*  author_idx = (const int*)d_in[1];
    const void* embed      = d_in[2];
    const int* esrc[3] = { (const int*)d_in[17], (const int*)d_in[19], (const int*)d_in[21] };
    const int* edst[3] = { (const int*)d_in[18], (const int*)d_in[20], (const int*)d_in[22] };

    // workspace (256B-aligned carve-outs), ~210 MB total via liveness overlays:
    //   region R: Q-papers (dead after edge_fused) overlaid with ACC-authors
    //             (written by edge_gather, read by author epilogue)
    //   ACC-papers front: CSR-build scratch (rankb/cntb/bsumb, dead after build)
    uint8_t* p = (uint8_t*)d_ws;
    auto take = [&](size_t bytes) {
        uint8_t* q = p; p += (bytes + 255) & ~(size_t)255; return q;
    };
    bf16*  XS   = (bf16*) take((size_t)NTOT * HID * 2);   // papers | authors (padded)
    uint8_t* R  = take((size_t)NAPAD * HID * 4);          // max(Qp bf16, ACCa f32)
    bf16*  Qp   = (bf16*) R;                              // [NPAD x 128]
    float* ACCa = (float*)R;                              // [NAPAD x 128]
    bf16*  Qa   = (bf16*) take((size_t)NAPAD * HID * 2);
    bf16*  KV   = (bf16*) take((size_t)NTOT * 256 * 2);   // interleaved [K|V] rows
    float* ACCp = (float*)take((size_t)NPAD * HID * 4);
    bf16*  WCT  = (bf16*) take((size_t)6 * 16384 * 2);
    float* BC   = (float*)take((size_t)6 * 128 * 4);
    bf16*  WB   = (bf16*) take((size_t)O_WTOT * 2);
    bf16*  WTS  = (bf16*) take((size_t)9 * 16384 * 2);
    float* BF32 = (float*)take((size_t)9 * 128 * 4);
    int*   flag = (int*)  take(256);
    int Ndv[3] = { NPAPER, NAUTHOR, NPAPER };
    int* CSRoff[3];
    for (int e = 0; e < 3; ++e) CSRoff[e] = (int*)take((size_t)Ndv[e] * 4);
    int* CSRsrc[3];
    for (int e = 0; e < 3; ++e) CSRsrc[e] = (int*)take((size_t)NEDGE * 4);
    // CSR-build scratch overlaid on ACC-papers (dead once CSR built)
    int* rankb = (int*)ACCp;
    int* cntb  = rankb + NEDGE;
    int* bsumb = cntb + NPAPER;

    bf16* XSa = XS + (size_t)NPAD * HID;    // author region

    detect_kernel<<<1, 64, 0, stream>>>(d_in[13], flag);
    convert_weights<<<(O_WTOT + 255)/256, 256, 0, stream>>>(
        d_in[3], d_in[4], d_in[5], d_in[6], d_in[7], d_in[8], d_in[9], d_in[10],
        d_in[11], d_in[12], d_in[13], d_in[14], d_in[15], d_in[16], WB, flag);
    transpose_static<<<(9*16384 + 255)/256, 256, 0, stream>>>(WB, WTS);
    bias_prep<<<(9*128 + 255)/256, 256, 0, stream>>>(WB, BF32);

    // ---- CSR per edge type (e=0 srcs pre-offset into author KV region) ----
    const int EB = (NEDGE + 255) / 256;
    for (int e = 0; e < 3; ++e) {
        int Nd = Ndv[e];
        int nb = (Nd + 255) / 256;
        hipMemsetAsync(cntb, 0, (size_t)Nd * sizeof(int), stream);
        hist_kernel<<<EB, 256, 0, stream>>>(edst[e], cntb, rankb, NEDGE);
        scan1_kernel<<<nb, 256, 0, stream>>>(cntb, CSRoff[e], bsumb, Nd);
        scan2_kernel<<<1, 512, 0, stream>>>(bsumb, nb);
        scan3_kernel<<<nb, 256, 0, stream>>>(CSRoff[e], bsumb, Nd);
        fill_kernel<<<EB, 256, 0, stream>>>(esrc[e], edst[e], CSRoff[e], rankb,
                                            CSRsrc[e], NEDGE, (e == 0) ? NPAD : 0);
    }

    // ---- input projections ----
    gemm_proj<2,1><<<(NPAPER + 63)/64, 256, 0, stream>>>(
        x_paper, WTS, WTS, BF32, BF32, nullptr, nullptr, nullptr, nullptr,
        XS, nullptr, 128, NPAPER, NPAD, flag);
    gather_embed<<<(NAUTHOR*16 + 255)/256, 256, 0, stream>>>(embed, author_idx, XSa, NAUTHOR, flag);

    for (int l = 0; l < 2; ++l) {
        combine_kernel<<<6, 256, 0, stream>>>(WB + O_KW, WB + O_KB, WB + O_VW, WB + O_VB,
                                              WB + O_AREL, WB + O_MREL, l, WCT, BC);
        // Q projection, split (Qp and ACCa share a region -> non-contiguous Q)
        gemm_proj<0,1><<<NPAD/64, 256, 0, stream>>>(
            XS, WTS + (size_t)(1 + l*2)*16384, WTS + (size_t)(1 + l*2)*16384,
            BF32 + (1 + l*2)*128, BF32 + (1 + l*2)*128,
            nullptr, nullptr, nullptr, nullptr,
            Qp, nullptr, 128, NPAD, NPAD, flag);
        gemm_proj<0,1><<<NAPAD/64, 256, 0, stream>>>(
            XSa, WTS + (size_t)(2 + l*2)*16384, WTS + (size_t)(2 + l*2)*16384,
            BF32 + (2 + l*2)*128, BF32 + (2 + l*2)*128,
            nullptr, nullptr, nullptr, nullptr,
            Qa, nullptr, 128, NAPAD, NAPAD, flag);

        // K/V for paper-dst edges: papers get cites(e2) weights, authors get
        // writes(e0) weights; interleaved KV rows over all NTOT rows.
        gemm_proj<0,2><<<NTOT/64, 256, 0, stream>>>(
            XS,
            WCT + (size_t)4*16384, WCT + (size_t)0*16384,   // K
            BC + 4*128, BC + 0*128,
            WCT + (size_t)5*16384, WCT + (size_t)1*16384,   // V
            BC + 5*128, BC + 1*128,
            KV, KV + 128, 256,
            NTOT, NPAD, flag);

        // fused paper-dst aggregation: writes (author srcs, +NPAD rows) +
        // cites (paper srcs); separate softmax each; single ACC write.
        edge_fused<<<(NPAPER*32 + 255)/256, 256, 0, stream>>>(
            Qp, KV, CSRoff[0], CSRsrc[0], CSRoff[2], CSRsrc[2],
            WB + O_PREL + (l*3 + 0)*4, WB + O_PREL + (l*3 + 2)*4,
            ACCp, NPAPER, NEDGE);

        // K/V for author-dst edges (rev_writes e1, paper srcs): overwrite
        // paper rows of KV (fused kernel is done with them).
        gemm_proj<0,2><<<NPAD/64, 256, 0, stream>>>(
            XS,
            WCT + (size_t)2*16384, WCT + (size_t)2*16384,
            BC + 2*128, BC + 2*128,
            WCT + (size_t)3*16384, WCT + (size_t)3*16384,
            BC + 3*128, BC + 3*128,
            KV, KV + 128, 256,
            NPAD, NPAD + 64, flag);

        // author-dst aggregation; ACCa overwrites Qp region (Qp now dead)
        edge_gather<<<(NAUTHOR*32 + 255)/256, 256, 0, stream>>>(
            Qa, KV, CSRoff[1], CSRsrc[1],
            WB + O_PREL + (l*3 + 1)*4, ACCa, NAUTHOR, NEDGE);

        // fused epilogue, split (ACCp / ACCa non-contiguous)
        gemm_epi<<<NPAD/64, 256, 0, stream>>>(
            ACCp, WTS + (size_t)(5 + l*2)*16384, WTS + (size_t)(5 + l*2)*16384,
            BF32 + (5 + l*2)*128, BF32 + (5 + l*2)*128,
            WB + O_SKIP + l*2, XS, NPAD);
        gemm_epi<<<NAPAD/64, 256, 0, stream>>>(
            ACCa, WTS + (size_t)(6 + l*2)*16384, WTS + (size_t)(6 + l*2)*16384,
            BF32 + (6 + l*2)*128, BF32 + (6 + l*2)*128,
            WB + O_SKIP + l*2, XSa, 0);
    }

    int total8 = (BATCH_PAPER + BATCH_AUTHOR) * 16;
    copy_out<<<(total8 + 255)/256, 256, 0, stream>>>(XS, d_out, total8, flag);
}